// Round 2
// baseline (621.615 us; speedup 1.0000x reference)
//
#include <hip/hip_runtime.h>

typedef __bf16 bfv8 __attribute__((ext_vector_type(8)));
typedef float f32x4 __attribute__((ext_vector_type(4)));
#define MFMA16(a,b,c) __builtin_amdgcn_mfma_f32_16x16x32_bf16(a,b,c,0,0,0)

constexpr int C      = 128;
constexpr int HD     = 32;
constexpr int NTOK   = 343;     // tokens per window (7^3)
constexpr int ROWS   = 43904;   // B*H*W*D = 2*28^3
constexpr int HIDDEN = 512;
constexpr float SCALE = 0.17677669529663687f;  // 32^-0.5
constexpr float EPS   = 1e-5f;

static __device__ __forceinline__ float b2f(ushort u) {
  union { unsigned int i; float f; } x; x.i = ((unsigned int)u) << 16; return x.f;
}
static __device__ __forceinline__ ushort f2b(float f) {
  union { float f; unsigned int i; } x; x.f = f;
  unsigned int r = x.i + 0x7fffu + ((x.i >> 16) & 1u);
  return (ushort)(r >> 16);
}

// dest row (window layout) -> source row (original layout), includes roll by 3
static __device__ __forceinline__ int perm_row(int row) {
  int win = row / NTOK, tok = row - win * NTOK;
  int bb = win >> 6, wi = win & 63;
  int a  = wi >> 4, w2 = (wi >> 2) & 3, c2 = wi & 3;
  int t1 = tok / 49, rem = tok - t1 * 49;
  int t2 = rem / 7,  t3 = rem - t2 * 7;
  int gh = a * 7 + t1 + 3;  if (gh >= 28) gh -= 28;
  int gw = w2 * 7 + t2 + 3; if (gw >= 28) gw -= 28;
  int gd = c2 * 7 + t3 + 3; if (gd >= 28) gd -= 28;
  return bb * 21952 + gh * 784 + gw * 28 + gd;
}

// ---------------- f32 -> bf16 weight conversion ----------------
__global__ __launch_bounds__(256) void cvt_kernel(const float* __restrict__ s0,
                                                  const float* __restrict__ s1,
                                                  const float* __restrict__ s2,
                                                  const float* __restrict__ s3,
                                                  ushort* __restrict__ d0,
                                                  ushort* __restrict__ d1,
                                                  ushort* __restrict__ d2,
                                                  ushort* __restrict__ d3) {
  int t = blockIdx.x * 256 + threadIdx.x;
  if (t < 49152)       d0[t]          = f2b(s0[t]);
  else if (t < 65536)  d1[t - 49152]  = f2b(s1[t - 49152]);
  else if (t < 131072) d2[t - 65536]  = f2b(s2[t - 65536]);
  else                 d3[t - 131072] = f2b(s3[t - 131072]);
}

// ---------------- relative position bias materialization ----------------
__global__ __launch_bounds__(256) void bias_kernel(const int* __restrict__ rel,
                                                   const float* __restrict__ tab,
                                                   float* __restrict__ bias) {
  int t = blockIdx.x * 256 + threadIdx.x;
  if (t >= NTOK * NTOK) return;
  int idx = rel[t];
  #pragma unroll
  for (int h = 0; h < 4; ++h)
    bias[h * (NTOK * NTOK) + t] = tab[idx * 4 + h];
}

// ---------------- LayerNorm (optionally with roll+window permutation), f32 in -> bf16 out ----
template<bool PERM>
__global__ __launch_bounds__(256) void ln_kernel(const float* __restrict__ in,
                                                 const float* __restrict__ w,
                                                 const float* __restrict__ b,
                                                 ushort* __restrict__ out) {
  int wid = threadIdx.x >> 6, lane = threadIdx.x & 63;
  int row = blockIdx.x * 4 + wid;
  int src = PERM ? perm_row(row) : row;
  float2 v = *reinterpret_cast<const float2*>(in + (size_t)src * C + lane * 2);
  float s = v.x + v.y, q = v.x * v.x + v.y * v.y;
  #pragma unroll
  for (int off = 32; off; off >>= 1) { s += __shfl_xor(s, off); q += __shfl_xor(q, off); }
  float mu = s * (1.0f / 128.0f);
  float var = q * (1.0f / 128.0f) - mu * mu;
  float rs = rsqrtf(var + EPS);
  int c = lane * 2;
  ushort2 ov;
  ov.x = f2b((v.x - mu) * rs * w[c]     + b[c]);
  ov.y = f2b((v.y - mu) * rs * w[c + 1] + b[c + 1]);
  *reinterpret_cast<ushort2*>(out + (size_t)row * C + c) = ov;
}

// ---------------- generic 64x64-tile bf16 MFMA GEMM with fused epilogues ----------------
// acc[m][n] = sum_k A[m][k] * W[n][k]  (+bias, +epilogue)
// EPI 0: QKV scatter (bf16)  1: proj + residual(f32 x) -> f32 y, un-permute
// EPI 2: gelu -> bf16 h1     3: mlp2 + residual(f32 y) -> f32 out
template<int KTOT, int EPI>
__global__ __launch_bounds__(256) void gemm_kernel(const ushort* __restrict__ A,
                                                   const ushort* __restrict__ W,
                                                   const float* __restrict__ bias,
                                                   const float* __restrict__ X,
                                                   ushort* __restrict__ O0,
                                                   ushort* __restrict__ O1,
                                                   ushort* __restrict__ O2,
                                                   float* __restrict__ OF) {
  __shared__ ushort Al[64][136];
  __shared__ ushort Bl[64][136];
  const int m0 = blockIdx.x * 64, n0 = blockIdx.y * 64;
  const int tid = threadIdx.x, lane = tid & 63, wid = tid >> 6;
  const int wr = wid >> 1, wc = wid & 1;
  const int lr = lane & 15, kb0 = (lane >> 4) * 8;
  const int sr = tid >> 4, sc = (tid & 15) * 8;
  f32x4 acc[2][2] = {};
  for (int kc = 0; kc < KTOT; kc += 128) {
    #pragma unroll
    for (int p = 0; p < 4; ++p) {
      int row = p * 16 + sr;
      *reinterpret_cast<int4*>(&Al[row][sc]) =
          *reinterpret_cast<const int4*>(&A[(size_t)(m0 + row) * KTOT + kc + sc]);
      *reinterpret_cast<int4*>(&Bl[row][sc]) =
          *reinterpret_cast<const int4*>(&W[(size_t)(n0 + row) * KTOT + kc + sc]);
    }
    __syncthreads();
    #pragma unroll
    for (int kk = 0; kk < 4; ++kk) {
      int kb = kk * 32 + kb0;
      bfv8 a0 = *reinterpret_cast<const bfv8*>(&Al[wr * 32 + lr][kb]);
      bfv8 a1 = *reinterpret_cast<const bfv8*>(&Al[wr * 32 + 16 + lr][kb]);
      bfv8 b0 = *reinterpret_cast<const bfv8*>(&Bl[wc * 32 + lr][kb]);
      bfv8 b1 = *reinterpret_cast<const bfv8*>(&Bl[wc * 32 + 16 + lr][kb]);
      acc[0][0] = MFMA16(a0, b0, acc[0][0]);
      acc[0][1] = MFMA16(a0, b1, acc[0][1]);
      acc[1][0] = MFMA16(a1, b0, acc[1][0]);
      acc[1][1] = MFMA16(a1, b1, acc[1][1]);
    }
    __syncthreads();
  }
  #pragma unroll
  for (int m = 0; m < 2; ++m)
    #pragma unroll
    for (int n = 0; n < 2; ++n)
      #pragma unroll
      for (int r = 0; r < 4; ++r) {
        int gm = m0 + wr * 32 + m * 16 + (lane >> 4) * 4 + r;
        int gn = n0 + wc * 32 + n * 16 + (lane & 15);
        float v = acc[m][n][r] + bias[gn];
        if (EPI == 0) {
          int which = gn >> 7, head = (gn >> 5) & 3, d = gn & 31;
          int win = gm / NTOK, tok = gm - win * NTOK;
          ushort* dst = (which == 0) ? O0 : (which == 1) ? O1 : O2;
          dst[((win * 4 + head) * NTOK + tok) * HD + d] = f2b(v);
        } else if (EPI == 1) {
          int orig = perm_row(gm);
          OF[(size_t)orig * C + gn] = v + X[(size_t)orig * C + gn];
        } else if (EPI == 2) {
          float g = 0.5f * v * (1.0f + erff(v * 0.70710678118654752f));
          O0[(size_t)gm * HIDDEN + gn] = f2b(g);
        } else {
          OF[(size_t)gm * C + gn] = v + X[(size_t)gm * C + gn];
        }
      }
}

// ---------------- windowed attention: one wave per (window, head) ----------------
__global__ __launch_bounds__(64, 1) void attn_kernel(const ushort* __restrict__ Q,
                                                     const ushort* __restrict__ K,
                                                     const ushort* __restrict__ V,
                                                     const float* __restrict__ bias,
                                                     ushort* __restrict__ out) {
  __shared__ ushort vt[32][360];   // V transposed: vt[d][token]
  __shared__ ushort pl[16][360];   // P tile (16 query rows x 352 keys)
  const int wh = blockIdx.x;
  const int win = wh >> 2, head = wh & 3;
  const int lane = threadIdx.x;
  for (int t = lane; t < 352; t += 64) {
    if (t < NTOK) {
      ushort tmp[32];
      const ushort* vr = V + ((size_t)wh * NTOK + t) * HD;
      *reinterpret_cast<int4*>(&tmp[0])  = *reinterpret_cast<const int4*>(vr);
      *reinterpret_cast<int4*>(&tmp[8])  = *reinterpret_cast<const int4*>(vr + 8);
      *reinterpret_cast<int4*>(&tmp[16]) = *reinterpret_cast<const int4*>(vr + 16);
      *reinterpret_cast<int4*>(&tmp[24]) = *reinterpret_cast<const int4*>(vr + 24);
      #pragma unroll
      for (int d = 0; d < 32; ++d) vt[d][t] = tmp[d];
    } else {
      #pragma unroll
      for (int d = 0; d < 32; ++d) vt[d][t] = 0;
    }
  }
  __syncthreads();
  const int lr = lane & 15, kb0 = (lane >> 4) * 8;
  const int key = lane & 15;
  const float* bh = bias + head * (NTOK * NTOK);
  for (int mt = 0; mt < 22; ++mt) {
    int qrow = mt * 16 + lr; if (qrow > 342) qrow = 342;   // clamp pad rows
    bfv8 aq = *reinterpret_cast<const bfv8*>(Q + ((size_t)wh * NTOK + qrow) * HD + kb0);
    f32x4 s[22];
    #pragma unroll
    for (int nt = 0; nt < 22; ++nt) {
      int krow = nt * 16 + lr; if (krow > 342) krow = 342;
      bfv8 bk = *reinterpret_cast<const bfv8*>(K + ((size_t)wh * NTOK + krow) * HD + kb0);
      f32x4 z = {};
      s[nt] = MFMA16(aq, bk, z);
    }
    // softmax over keys (row = mt*16 + (lane>>4)*4 + r, col = nt*16 + (lane&15))
    int qbase = mt * 16 + (lane >> 4) * 4;
    float mx[4] = {-3e38f, -3e38f, -3e38f, -3e38f};
    #pragma unroll
    for (int nt = 0; nt < 22; ++nt) {
      int k = nt * 16 + key;
      #pragma unroll
      for (int r = 0; r < 4; ++r) {
        int q = qbase + r;
        float v = (k < NTOK && q < NTOK) ? s[nt][r] * SCALE + bh[q * NTOK + k] : -3e38f;
        s[nt][r] = v;
        mx[r] = fmaxf(mx[r], v);
      }
    }
    #pragma unroll
    for (int r = 0; r < 4; ++r) {
      #pragma unroll
      for (int off = 1; off < 16; off <<= 1) mx[r] = fmaxf(mx[r], __shfl_xor(mx[r], off));
    }
    float sm[4] = {0.f, 0.f, 0.f, 0.f};
    #pragma unroll
    for (int nt = 0; nt < 22; ++nt)
      #pragma unroll
      for (int r = 0; r < 4; ++r) {
        float p = __expf(s[nt][r] - mx[r]);
        s[nt][r] = p; sm[r] += p;
      }
    #pragma unroll
    for (int r = 0; r < 4; ++r) {
      #pragma unroll
      for (int off = 1; off < 16; off <<= 1) sm[r] += __shfl_xor(sm[r], off);
    }
    float inv[4];
    #pragma unroll
    for (int r = 0; r < 4; ++r) inv[r] = 1.0f / sm[r];
    #pragma unroll
    for (int nt = 0; nt < 22; ++nt) {
      int kcol = nt * 16 + key;
      #pragma unroll
      for (int r = 0; r < 4; ++r)
        pl[(lane >> 4) * 4 + r][kcol] = f2b(s[nt][r] * inv[r]);
    }
    __syncthreads();
    // PV: O[16 x 32] = P[16 x 352] * V[352 x 32]
    f32x4 o0 = {}, o1 = {};
    #pragma unroll
    for (int kt = 0; kt < 11; ++kt) {
      bfv8 ap  = *reinterpret_cast<const bfv8*>(&pl[lr][kt * 32 + kb0]);
      bfv8 bv0 = *reinterpret_cast<const bfv8*>(&vt[lr][kt * 32 + kb0]);
      bfv8 bv1 = *reinterpret_cast<const bfv8*>(&vt[16 + lr][kt * 32 + kb0]);
      o0 = MFMA16(ap, bv0, o0);
      o1 = MFMA16(ap, bv1, o1);
    }
    #pragma unroll
    for (int r = 0; r < 4; ++r) {
      int q = qbase + r;
      if (q < NTOK) {
        out[((size_t)(win * NTOK + q)) * C + head * HD + key]      = f2b(o0[r]);
        out[((size_t)(win * NTOK + q)) * C + head * HD + 16 + key] = f2b(o1[r]);
      }
    }
    __syncthreads();
  }
}

// ---------------- launcher ----------------
extern "C" void kernel_launch(void* const* d_in, const int* in_sizes, int n_in,
                              void* d_out, int out_size, void* d_ws, size_t ws_size,
                              hipStream_t stream) {
  const float* x     = (const float*)d_in[0];
  const float* n1w   = (const float*)d_in[1];
  const float* n1b   = (const float*)d_in[2];
  const float* qkvw  = (const float*)d_in[3];
  const float* qkvb  = (const float*)d_in[4];
  const float* rpb   = (const float*)d_in[5];
  const float* projw = (const float*)d_in[6];
  const float* projb = (const float*)d_in[7];
  const float* n2w   = (const float*)d_in[8];
  const float* n2b   = (const float*)d_in[9];
  const float* w1    = (const float*)d_in[10];
  const float* b1    = (const float*)d_in[11];
  const float* w2    = (const float*)d_in[12];
  const float* b2    = (const float*)d_in[13];
  const int*   rel   = (const int*)d_in[14];

  char* ws = (char*)d_ws;
  constexpr size_t SZ_ACT  = (size_t)ROWS * C * 2;          // 11,239,424 (bf16 activations)
  constexpr size_t SZ_BIAS = (size_t)4 * NTOK * NTOK * 4;   // 1,882,384

  ushort* lnbuf  = (ushort*)(ws);                           // LN1 out, later LN2 out
  ushort* Qb     = (ushort*)(ws + SZ_ACT);
  ushort* Kb     = (ushort*)(ws + 2 * SZ_ACT);
  ushort* Vb     = (ushort*)(ws + 3 * SZ_ACT);
  float*  bias   = (float*)(ws + 4 * SZ_ACT);
  size_t off_att = (4 * SZ_ACT + SZ_BIAS + 255) & ~(size_t)255;   // 46,840,320
  ushort* attout = (ushort*)(ws + off_att);
  ushort* h1     = Qb;                                      // overlay Qb..attout (dead by MLP1)
  size_t off_y   = off_att + SZ_ACT;                        // 58,079,744
  float*  y      = (float*)(ws + off_y);
  size_t off_w   = off_y + (size_t)ROWS * C * 4;            // 80,558,592
  ushort* wqkv   = (ushort*)(ws + off_w);
  ushort* wproj  = (ushort*)(ws + off_w + 98304);
  ushort* wm1    = (ushort*)(ws + off_w + 131072);
  ushort* wm2    = (ushort*)(ws + off_w + 262144);
  float*  outp   = (float*)d_out;

  cvt_kernel<<<768, 256, 0, stream>>>(qkvw, projw, w1, w2, wqkv, wproj, wm1, wm2);
  bias_kernel<<<(NTOK * NTOK + 255) / 256, 256, 0, stream>>>(rel, rpb, bias);
  ln_kernel<true><<<ROWS / 4, 256, 0, stream>>>(x, n1w, n1b, lnbuf);
  gemm_kernel<128, 0><<<dim3(ROWS / 64, 6), 256, 0, stream>>>(lnbuf, wqkv, qkvb, nullptr, Qb, Kb, Vb, nullptr);
  attn_kernel<<<512, 64, 0, stream>>>(Qb, Kb, Vb, bias, attout);
  gemm_kernel<128, 1><<<dim3(ROWS / 64, 2), 256, 0, stream>>>(attout, wproj, projb, x, nullptr, nullptr, nullptr, y);
  ln_kernel<false><<<ROWS / 4, 256, 0, stream>>>(y, n2w, n2b, lnbuf);
  gemm_kernel<128, 2><<<dim3(ROWS / 64, 8), 256, 0, stream>>>(lnbuf, wm1, b1, nullptr, h1, nullptr, nullptr, nullptr);
  gemm_kernel<512, 3><<<dim3(ROWS / 64, 2), 256, 0, stream>>>(h1, wm2, b2, y, nullptr, nullptr, nullptr, outp);
}

// Round 3
// 376.873 us; speedup vs baseline: 1.6494x; 1.6494x over previous
//
#include <hip/hip_runtime.h>

typedef __bf16 bfv8 __attribute__((ext_vector_type(8)));
typedef float f32x4 __attribute__((ext_vector_type(4)));
#define MFMA16(a,b,c) __builtin_amdgcn_mfma_f32_16x16x32_bf16(a,b,c,0,0,0)

constexpr int C      = 128;
constexpr int HD     = 32;
constexpr int NTOK   = 343;     // tokens per window (7^3)
constexpr int ROWS   = 43904;   // B*H*W*D = 2*28^3
constexpr int HIDDEN = 512;
constexpr float SCALE = 0.17677669529663687f;  // 32^-0.5
constexpr float EPS   = 1e-5f;

static __device__ __forceinline__ float b2f(ushort u) {
  union { unsigned int i; float f; } x; x.i = ((unsigned int)u) << 16; return x.f;
}
static __device__ __forceinline__ ushort f2b(float f) {
  union { float f; unsigned int i; } x; x.f = f;
  unsigned int r = x.i + 0x7fffu + ((x.i >> 16) & 1u);
  return (ushort)(r >> 16);
}

// dest row (window layout) -> source row (original layout), includes roll by 3
static __device__ __forceinline__ int perm_row(int row) {
  int win = row / NTOK, tok = row - win * NTOK;
  int bb = win >> 6, wi = win & 63;
  int a  = wi >> 4, w2 = (wi >> 2) & 3, c2 = wi & 3;
  int t1 = tok / 49, rem = tok - t1 * 49;
  int t2 = rem / 7,  t3 = rem - t2 * 7;
  int gh = a * 7 + t1 + 3;  if (gh >= 28) gh -= 28;
  int gw = w2 * 7 + t2 + 3; if (gw >= 28) gw -= 28;
  int gd = c2 * 7 + t3 + 3; if (gd >= 28) gd -= 28;
  return bb * 21952 + gh * 784 + gw * 28 + gd;
}

// ---------------- f32 -> bf16 weight conversion ----------------
__global__ __launch_bounds__(256) void cvt_kernel(const float* __restrict__ s0,
                                                  const float* __restrict__ s1,
                                                  const float* __restrict__ s2,
                                                  const float* __restrict__ s3,
                                                  ushort* __restrict__ d0,
                                                  ushort* __restrict__ d1,
                                                  ushort* __restrict__ d2,
                                                  ushort* __restrict__ d3) {
  int t = blockIdx.x * 256 + threadIdx.x;
  if (t < 49152)       d0[t]          = f2b(s0[t]);
  else if (t < 65536)  d1[t - 49152]  = f2b(s1[t - 49152]);
  else if (t < 131072) d2[t - 65536]  = f2b(s2[t - 65536]);
  else                 d3[t - 131072] = f2b(s3[t - 131072]);
}

// ---------------- relative position bias materialization ----------------
__global__ __launch_bounds__(256) void bias_kernel(const int* __restrict__ rel,
                                                   const float* __restrict__ tab,
                                                   float* __restrict__ bias) {
  int t = blockIdx.x * 256 + threadIdx.x;
  if (t >= NTOK * NTOK) return;
  int idx = rel[t];
  #pragma unroll
  for (int h = 0; h < 4; ++h)
    bias[h * (NTOK * NTOK) + t] = tab[idx * 4 + h];
}

// ---------------- LayerNorm (optionally with roll+window permutation), f32 in -> bf16 out ----
template<bool PERM>
__global__ __launch_bounds__(256) void ln_kernel(const float* __restrict__ in,
                                                 const float* __restrict__ w,
                                                 const float* __restrict__ b,
                                                 ushort* __restrict__ out) {
  int wid = threadIdx.x >> 6, lane = threadIdx.x & 63;
  int row = blockIdx.x * 4 + wid;
  int src = PERM ? perm_row(row) : row;
  float2 v = *reinterpret_cast<const float2*>(in + (size_t)src * C + lane * 2);
  float s = v.x + v.y, q = v.x * v.x + v.y * v.y;
  #pragma unroll
  for (int off = 32; off; off >>= 1) { s += __shfl_xor(s, off); q += __shfl_xor(q, off); }
  float mu = s * (1.0f / 128.0f);
  float var = q * (1.0f / 128.0f) - mu * mu;
  float rs = rsqrtf(var + EPS);
  int c = lane * 2;
  ushort2 ov;
  ov.x = f2b((v.x - mu) * rs * w[c]     + b[c]);
  ov.y = f2b((v.y - mu) * rs * w[c + 1] + b[c + 1]);
  *reinterpret_cast<ushort2*>(out + (size_t)row * C + c) = ov;
}

// ---------------- generic 64x64-tile bf16 MFMA GEMM with fused epilogues ----------------
// acc[m][n] = sum_k A[m][k] * W[n][k]  (+bias, +epilogue)
// EPI 0: QKV scatter (bf16)  1: proj + residual(f32 x) -> f32 y, un-permute
// EPI 2: gelu -> bf16 h1     3: mlp2 + residual(f32 y) -> f32 out
template<int KTOT, int EPI>
__global__ __launch_bounds__(256) void gemm_kernel(const ushort* __restrict__ A,
                                                   const ushort* __restrict__ W,
                                                   const float* __restrict__ bias,
                                                   const float* __restrict__ X,
                                                   ushort* __restrict__ O0,
                                                   ushort* __restrict__ O1,
                                                   ushort* __restrict__ O2,
                                                   float* __restrict__ OF) {
  __shared__ ushort Al[64][136];
  __shared__ ushort Bl[64][136];
  const int m0 = blockIdx.x * 64, n0 = blockIdx.y * 64;
  const int tid = threadIdx.x, lane = tid & 63, wid = tid >> 6;
  const int wr = wid >> 1, wc = wid & 1;
  const int lr = lane & 15, kb0 = (lane >> 4) * 8;
  const int sr = tid >> 4, sc = (tid & 15) * 8;
  f32x4 acc[2][2] = {};
  for (int kc = 0; kc < KTOT; kc += 128) {
    #pragma unroll
    for (int p = 0; p < 4; ++p) {
      int row = p * 16 + sr;
      *reinterpret_cast<int4*>(&Al[row][sc]) =
          *reinterpret_cast<const int4*>(&A[(size_t)(m0 + row) * KTOT + kc + sc]);
      *reinterpret_cast<int4*>(&Bl[row][sc]) =
          *reinterpret_cast<const int4*>(&W[(size_t)(n0 + row) * KTOT + kc + sc]);
    }
    __syncthreads();
    #pragma unroll
    for (int kk = 0; kk < 4; ++kk) {
      int kb = kk * 32 + kb0;
      bfv8 a0 = *reinterpret_cast<const bfv8*>(&Al[wr * 32 + lr][kb]);
      bfv8 a1 = *reinterpret_cast<const bfv8*>(&Al[wr * 32 + 16 + lr][kb]);
      bfv8 b0 = *reinterpret_cast<const bfv8*>(&Bl[wc * 32 + lr][kb]);
      bfv8 b1 = *reinterpret_cast<const bfv8*>(&Bl[wc * 32 + 16 + lr][kb]);
      acc[0][0] = MFMA16(a0, b0, acc[0][0]);
      acc[0][1] = MFMA16(a0, b1, acc[0][1]);
      acc[1][0] = MFMA16(a1, b0, acc[1][0]);
      acc[1][1] = MFMA16(a1, b1, acc[1][1]);
    }
    __syncthreads();
  }
  #pragma unroll
  for (int m = 0; m < 2; ++m)
    #pragma unroll
    for (int n = 0; n < 2; ++n)
      #pragma unroll
      for (int r = 0; r < 4; ++r) {
        int gm = m0 + wr * 32 + m * 16 + (lane >> 4) * 4 + r;
        int gn = n0 + wc * 32 + n * 16 + (lane & 15);
        float v = acc[m][n][r] + bias[gn];
        if (EPI == 0) {
          int which = gn >> 7, head = (gn >> 5) & 3, d = gn & 31;
          int win = gm / NTOK, tok = gm - win * NTOK;
          ushort* dst = (which == 0) ? O0 : (which == 1) ? O1 : O2;
          dst[((win * 4 + head) * NTOK + tok) * HD + d] = f2b(v);
        } else if (EPI == 1) {
          int orig = perm_row(gm);
          OF[(size_t)orig * C + gn] = v + X[(size_t)orig * C + gn];
        } else if (EPI == 2) {
          float g = 0.5f * v * (1.0f + erff(v * 0.70710678118654752f));
          O0[(size_t)gm * HIDDEN + gn] = f2b(g);
        } else {
          OF[(size_t)gm * C + gn] = v + X[(size_t)gm * C + gn];
        }
      }
}

// ---------------- windowed attention: one block (4 waves) per (window, head) ----------------
// Waves stride over the 22 query tiles; V^T staged once per block; per-wave P buffer
// so the main loop has NO barriers (intra-wave LDS deps ordered by lgkmcnt).
__global__ __launch_bounds__(256) void attn_kernel(const ushort* __restrict__ Q,
                                                   const ushort* __restrict__ K,
                                                   const ushort* __restrict__ V,
                                                   const float* __restrict__ bias,
                                                   ushort* __restrict__ out) {
  __shared__ ushort vt[32][360];      // V transposed: vt[d][token]
  __shared__ ushort pl[4][16][360];   // per-wave P tile (16 q-rows x 352 keys)
  const int wh = blockIdx.x;
  const int win = wh >> 2, head = wh & 3;
  const int tid = threadIdx.x, lane = tid & 63, wave = tid >> 6;
  // stage V transposed (all 4 waves cooperate), zero padding tokens
  for (int t = tid; t < 352; t += 256) {
    if (t < NTOK) {
      ushort tmp[32];
      const ushort* vr = V + ((size_t)wh * NTOK + t) * HD;
      *reinterpret_cast<int4*>(&tmp[0])  = *reinterpret_cast<const int4*>(vr);
      *reinterpret_cast<int4*>(&tmp[8])  = *reinterpret_cast<const int4*>(vr + 8);
      *reinterpret_cast<int4*>(&tmp[16]) = *reinterpret_cast<const int4*>(vr + 16);
      *reinterpret_cast<int4*>(&tmp[24]) = *reinterpret_cast<const int4*>(vr + 24);
      #pragma unroll
      for (int d = 0; d < 32; ++d) vt[d][t] = tmp[d];
    } else {
      #pragma unroll
      for (int d = 0; d < 32; ++d) vt[d][t] = 0;
    }
  }
  __syncthreads();
  const int lr = lane & 15, kb0 = (lane >> 4) * 8;
  const int key = lane & 15;
  const float* bh = bias + head * (NTOK * NTOK);
  for (int mt = wave; mt < 22; mt += 4) {
    int qrow = mt * 16 + lr; if (qrow > 342) qrow = 342;   // clamp pad rows
    bfv8 aq = *reinterpret_cast<const bfv8*>(Q + ((size_t)wh * NTOK + qrow) * HD + kb0);
    f32x4 s[22];
    #pragma unroll
    for (int nt = 0; nt < 22; ++nt) {
      int krow = nt * 16 + lr; if (krow > 342) krow = 342;
      bfv8 bk = *reinterpret_cast<const bfv8*>(K + ((size_t)wh * NTOK + krow) * HD + kb0);
      f32x4 z = {};
      s[nt] = MFMA16(aq, bk, z);
    }
    // softmax over keys (row = mt*16 + (lane>>4)*4 + r, col = nt*16 + (lane&15))
    int qbase = mt * 16 + (lane >> 4) * 4;
    float mx[4] = {-3e38f, -3e38f, -3e38f, -3e38f};
    #pragma unroll
    for (int nt = 0; nt < 22; ++nt) {
      int k = nt * 16 + key;
      #pragma unroll
      for (int r = 0; r < 4; ++r) {
        int q = qbase + r;
        float v = (k < NTOK && q < NTOK) ? s[nt][r] * SCALE + bh[q * NTOK + k] : -3e38f;
        s[nt][r] = v;
        mx[r] = fmaxf(mx[r], v);
      }
    }
    #pragma unroll
    for (int r = 0; r < 4; ++r) {
      #pragma unroll
      for (int off = 1; off < 16; off <<= 1) mx[r] = fmaxf(mx[r], __shfl_xor(mx[r], off));
    }
    float sm[4] = {0.f, 0.f, 0.f, 0.f};
    #pragma unroll
    for (int nt = 0; nt < 22; ++nt)
      #pragma unroll
      for (int r = 0; r < 4; ++r) {
        float p = __expf(s[nt][r] - mx[r]);
        s[nt][r] = p; sm[r] += p;
      }
    #pragma unroll
    for (int r = 0; r < 4; ++r) {
      #pragma unroll
      for (int off = 1; off < 16; off <<= 1) sm[r] += __shfl_xor(sm[r], off);
    }
    float inv[4];
    #pragma unroll
    for (int r = 0; r < 4; ++r) inv[r] = 1.0f / sm[r];
    #pragma unroll
    for (int nt = 0; nt < 22; ++nt) {
      int kcol = nt * 16 + key;
      #pragma unroll
      for (int r = 0; r < 4; ++r)
        pl[wave][(lane >> 4) * 4 + r][kcol] = f2b(s[nt][r] * inv[r]);
    }
    // PV: O[16 x 32] = P[16 x 352] * V[352 x 32]   (same-wave LDS dep, no barrier)
    f32x4 o0 = {}, o1 = {};
    #pragma unroll
    for (int kt = 0; kt < 11; ++kt) {
      bfv8 ap  = *reinterpret_cast<const bfv8*>(&pl[wave][lr][kt * 32 + kb0]);
      bfv8 bv0 = *reinterpret_cast<const bfv8*>(&vt[lr][kt * 32 + kb0]);
      bfv8 bv1 = *reinterpret_cast<const bfv8*>(&vt[16 + lr][kt * 32 + kb0]);
      o0 = MFMA16(ap, bv0, o0);
      o1 = MFMA16(ap, bv1, o1);
    }
    #pragma unroll
    for (int r = 0; r < 4; ++r) {
      int q = qbase + r;
      if (q < NTOK) {
        out[((size_t)(win * NTOK + q)) * C + head * HD + key]      = f2b(o0[r]);
        out[((size_t)(win * NTOK + q)) * C + head * HD + 16 + key] = f2b(o1[r]);
      }
    }
  }
}

// ---------------- launcher ----------------
extern "C" void kernel_launch(void* const* d_in, const int* in_sizes, int n_in,
                              void* d_out, int out_size, void* d_ws, size_t ws_size,
                              hipStream_t stream) {
  const float* x     = (const float*)d_in[0];
  const float* n1w   = (const float*)d_in[1];
  const float* n1b   = (const float*)d_in[2];
  const float* qkvw  = (const float*)d_in[3];
  const float* qkvb  = (const float*)d_in[4];
  const float* rpb   = (const float*)d_in[5];
  const float* projw = (const float*)d_in[6];
  const float* projb = (const float*)d_in[7];
  const float* n2w   = (const float*)d_in[8];
  const float* n2b   = (const float*)d_in[9];
  const float* w1    = (const float*)d_in[10];
  const float* b1    = (const float*)d_in[11];
  const float* w2    = (const float*)d_in[12];
  const float* b2    = (const float*)d_in[13];
  const int*   rel   = (const int*)d_in[14];

  char* ws = (char*)d_ws;
  constexpr size_t SZ_ACT  = (size_t)ROWS * C * 2;          // 11,239,424 (bf16 activations)
  constexpr size_t SZ_BIAS = (size_t)4 * NTOK * NTOK * 4;   // 1,882,384

  ushort* lnbuf  = (ushort*)(ws);                           // LN1 out, later LN2 out
  ushort* Qb     = (ushort*)(ws + SZ_ACT);
  ushort* Kb     = (ushort*)(ws + 2 * SZ_ACT);
  ushort* Vb     = (ushort*)(ws + 3 * SZ_ACT);
  float*  bias   = (float*)(ws + 4 * SZ_ACT);
  size_t off_att = (4 * SZ_ACT + SZ_BIAS + 255) & ~(size_t)255;   // 46,840,320
  ushort* attout = (ushort*)(ws + off_att);
  ushort* h1     = Qb;                                      // overlay Qb..attout (dead by MLP1)
  size_t off_y   = off_att + SZ_ACT;                        // 58,079,744
  float*  y      = (float*)(ws + off_y);
  size_t off_w   = off_y + (size_t)ROWS * C * 4;            // 80,558,592
  ushort* wqkv   = (ushort*)(ws + off_w);
  ushort* wproj  = (ushort*)(ws + off_w + 98304);
  ushort* wm1    = (ushort*)(ws + off_w + 131072);
  ushort* wm2    = (ushort*)(ws + off_w + 262144);
  float*  outp   = (float*)d_out;

  cvt_kernel<<<768, 256, 0, stream>>>(qkvw, projw, w1, w2, wqkv, wproj, wm1, wm2);
  bias_kernel<<<(NTOK * NTOK + 255) / 256, 256, 0, stream>>>(rel, rpb, bias);
  ln_kernel<true><<<ROWS / 4, 256, 0, stream>>>(x, n1w, n1b, lnbuf);
  gemm_kernel<128, 0><<<dim3(ROWS / 64, 6), 256, 0, stream>>>(lnbuf, wqkv, qkvb, nullptr, Qb, Kb, Vb, nullptr);
  attn_kernel<<<512, 256, 0, stream>>>(Qb, Kb, Vb, bias, attout);
  gemm_kernel<128, 1><<<dim3(ROWS / 64, 2), 256, 0, stream>>>(attout, wproj, projb, x, nullptr, nullptr, nullptr, y);
  ln_kernel<false><<<ROWS / 4, 256, 0, stream>>>(y, n2w, n2b, lnbuf);
  gemm_kernel<128, 2><<<dim3(ROWS / 64, 8), 256, 0, stream>>>(lnbuf, wm1, b1, nullptr, h1, nullptr, nullptr, nullptr);
  gemm_kernel<512, 3><<<dim3(ROWS / 64, 2), 256, 0, stream>>>(h1, wm2, b2, y, nullptr, nullptr, nullptr, outp);
}

// Round 4
// 154.914 us; speedup vs baseline: 4.0127x; 2.4328x over previous
//
#include <hip/hip_runtime.h>

typedef __bf16 bfv8 __attribute__((ext_vector_type(8)));
typedef float f32x4 __attribute__((ext_vector_type(4)));
#define MFMA16(a,b,c) __builtin_amdgcn_mfma_f32_16x16x32_bf16(a,b,c,0,0,0)

constexpr int C      = 128;
constexpr int HD     = 32;
constexpr int NTOK   = 343;     // tokens per window (7^3)
constexpr int ROWS   = 43904;   // B*H*W*D = 2*28^3
constexpr int HIDDEN = 512;
constexpr float SCALE = 0.17677669529663687f;  // 32^-0.5
constexpr float EPS   = 1e-5f;
constexpr int NT = 22;          // 16-row tiles per window (ceil(343/16))

static __device__ __forceinline__ float b2f(ushort u) {
  union { unsigned int i; float f; } x; x.i = ((unsigned int)u) << 16; return x.f;
}
static __device__ __forceinline__ ushort f2b(float f) {
  union { float f; unsigned int i; } x; x.f = f;
  unsigned int r = x.i + 0x7fffu + ((x.i >> 16) & 1u);
  return (ushort)(r >> 16);
}

// dest row (window layout) -> source row (original layout), includes roll by 3
static __device__ __forceinline__ int perm_row(int row) {
  int win = row / NTOK, tok = row - win * NTOK;
  int bb = win >> 6, wi = win & 63;
  int a  = wi >> 4, w2 = (wi >> 2) & 3, c2 = wi & 3;
  int t1 = tok / 49, rem = tok - t1 * 49;
  int t2 = rem / 7,  t3 = rem - t2 * 7;
  int gh = a * 7 + t1 + 3;  if (gh >= 28) gh -= 28;
  int gw = w2 * 7 + t2 + 3; if (gw >= 28) gw -= 28;
  int gd = c2 * 7 + t3 + 3; if (gd >= 28) gd -= 28;
  return bb * 21952 + gh * 784 + gw * 28 + gd;
}

// ---------------- f32 -> bf16 weight conversion ----------------
__global__ __launch_bounds__(256) void cvt_kernel(const float* __restrict__ s0,
                                                  const float* __restrict__ s1,
                                                  const float* __restrict__ s2,
                                                  const float* __restrict__ s3,
                                                  ushort* __restrict__ d0,
                                                  ushort* __restrict__ d1,
                                                  ushort* __restrict__ d2,
                                                  ushort* __restrict__ d3) {
  int t = blockIdx.x * 256 + threadIdx.x;
  if (t < 49152)       d0[t]          = f2b(s0[t]);
  else if (t < 65536)  d1[t - 49152]  = f2b(s1[t - 49152]);
  else if (t < 131072) d2[t - 65536]  = f2b(s2[t - 65536]);
  else                 d3[t - 131072] = f2b(s3[t - 131072]);
}

// ------- bias reordered into MFMA C-fragment order, mask baked in -------
// biasr[((head*NT + mt)*NT + nt)*64 + lane] = float4 (r = 0..3)
// element (q = mt*16 + (lane>>4)*4 + r, k = nt*16 + (lane&15)); pad -> -3e38
__global__ __launch_bounds__(256) void bias_kernel(const int* __restrict__ rel,
                                                   const float* __restrict__ tab,
                                                   float4* __restrict__ biasr) {
  int t = blockIdx.x * 256 + threadIdx.x;
  if (t >= 4 * NT * NT * 64) return;
  int lane = t & 63;
  int nt   = (t >> 6) % NT;
  int mt   = ((t >> 6) / NT) % NT;
  int head = t / (64 * NT * NT);
  int k  = nt * 16 + (lane & 15);
  int qb = mt * 16 + (lane >> 4) * 4;
  float vv[4];
  #pragma unroll
  for (int r = 0; r < 4; ++r) {
    int q = qb + r;
    if (q < NTOK && k < NTOK) {
      int idx = rel[q * NTOK + k];
      vv[r] = tab[idx * 4 + head];
    } else {
      vv[r] = -3e38f;
    }
  }
  biasr[t] = make_float4(vv[0], vv[1], vv[2], vv[3]);
}

// ---------------- LayerNorm (optionally with roll+window permutation), f32 in -> bf16 out ----
template<bool PERM>
__global__ __launch_bounds__(256) void ln_kernel(const float* __restrict__ in,
                                                 const float* __restrict__ w,
                                                 const float* __restrict__ b,
                                                 ushort* __restrict__ out) {
  int wid = threadIdx.x >> 6, lane = threadIdx.x & 63;
  int row = blockIdx.x * 4 + wid;
  int src = PERM ? perm_row(row) : row;
  float2 v = *reinterpret_cast<const float2*>(in + (size_t)src * C + lane * 2);
  float s = v.x + v.y, q = v.x * v.x + v.y * v.y;
  #pragma unroll
  for (int off = 32; off; off >>= 1) { s += __shfl_xor(s, off); q += __shfl_xor(q, off); }
  float mu = s * (1.0f / 128.0f);
  float var = q * (1.0f / 128.0f) - mu * mu;
  float rs = rsqrtf(var + EPS);
  int c = lane * 2;
  ushort2 ov;
  ov.x = f2b((v.x - mu) * rs * w[c]     + b[c]);
  ov.y = f2b((v.y - mu) * rs * w[c + 1] + b[c + 1]);
  *reinterpret_cast<ushort2*>(out + (size_t)row * C + c) = ov;
}

// ---------------- generic 64x64-tile bf16 MFMA GEMM with fused epilogues ----------------
// acc[m][n] = sum_k A[m][k] * W[n][k]  (+bias, +epilogue)
// EPI 0: QKV scatter (bf16, Q pre-scaled)  1: proj + residual(f32 x) -> f32 y, un-permute
// EPI 2: gelu -> bf16 h1                   3: mlp2 + residual(f32 y) -> f32 out
template<int KTOT, int EPI>
__global__ __launch_bounds__(256) void gemm_kernel(const ushort* __restrict__ A,
                                                   const ushort* __restrict__ W,
                                                   const float* __restrict__ bias,
                                                   const float* __restrict__ X,
                                                   ushort* __restrict__ O0,
                                                   ushort* __restrict__ O1,
                                                   ushort* __restrict__ O2,
                                                   float* __restrict__ OF) {
  __shared__ ushort Al[64][136];
  __shared__ ushort Bl[64][136];
  const int m0 = blockIdx.x * 64, n0 = blockIdx.y * 64;
  const int tid = threadIdx.x, lane = tid & 63, wid = tid >> 6;
  const int wr = wid >> 1, wc = wid & 1;
  const int lr = lane & 15, kb0 = (lane >> 4) * 8;
  const int sr = tid >> 4, sc = (tid & 15) * 8;
  f32x4 acc[2][2] = {};
  for (int kc = 0; kc < KTOT; kc += 128) {
    #pragma unroll
    for (int p = 0; p < 4; ++p) {
      int row = p * 16 + sr;
      *reinterpret_cast<int4*>(&Al[row][sc]) =
          *reinterpret_cast<const int4*>(&A[(size_t)(m0 + row) * KTOT + kc + sc]);
      *reinterpret_cast<int4*>(&Bl[row][sc]) =
          *reinterpret_cast<const int4*>(&W[(size_t)(n0 + row) * KTOT + kc + sc]);
    }
    __syncthreads();
    #pragma unroll
    for (int kk = 0; kk < 4; ++kk) {
      int kb = kk * 32 + kb0;
      bfv8 a0 = *reinterpret_cast<const bfv8*>(&Al[wr * 32 + lr][kb]);
      bfv8 a1 = *reinterpret_cast<const bfv8*>(&Al[wr * 32 + 16 + lr][kb]);
      bfv8 b0 = *reinterpret_cast<const bfv8*>(&Bl[wc * 32 + lr][kb]);
      bfv8 b1 = *reinterpret_cast<const bfv8*>(&Bl[wc * 32 + 16 + lr][kb]);
      acc[0][0] = MFMA16(a0, b0, acc[0][0]);
      acc[0][1] = MFMA16(a0, b1, acc[0][1]);
      acc[1][0] = MFMA16(a1, b0, acc[1][0]);
      acc[1][1] = MFMA16(a1, b1, acc[1][1]);
    }
    __syncthreads();
  }
  #pragma unroll
  for (int m = 0; m < 2; ++m)
    #pragma unroll
    for (int n = 0; n < 2; ++n)
      #pragma unroll
      for (int r = 0; r < 4; ++r) {
        int gm = m0 + wr * 32 + m * 16 + (lane >> 4) * 4 + r;
        int gn = n0 + wc * 32 + n * 16 + (lane & 15);
        float v = acc[m][n][r] + bias[gn];
        if (EPI == 0) {
          int which = gn >> 7, head = (gn >> 5) & 3, d = gn & 31;
          if (which == 0) v *= SCALE;     // fold attention scale into Q
          int win = gm / NTOK, tok = gm - win * NTOK;
          ushort* dst = (which == 0) ? O0 : (which == 1) ? O1 : O2;
          dst[((win * 4 + head) * NTOK + tok) * HD + d] = f2b(v);
        } else if (EPI == 1) {
          int orig = perm_row(gm);
          OF[(size_t)orig * C + gn] = v + X[(size_t)orig * C + gn];
        } else if (EPI == 2) {
          float g = 0.5f * v * (1.0f + erff(v * 0.70710678118654752f));
          O0[(size_t)gm * HIDDEN + gn] = f2b(g);
        } else {
          OF[(size_t)gm * C + gn] = v + X[(size_t)gm * C + gn];
        }
      }
}

// ---------------- windowed attention: one block (4 waves) per (window, head) ----------------
// bias pre-reordered as MFMA C operand (mask baked in); Q pre-scaled; P stored
// unnormalized; PV computed transposed (A = V^T, B = P) so outputs pack as ushort4.
__global__ __launch_bounds__(256) void attn_kernel(const ushort* __restrict__ Q,
                                                   const ushort* __restrict__ K,
                                                   const ushort* __restrict__ V,
                                                   const f32x4* __restrict__ biasr,
                                                   ushort* __restrict__ out) {
  __shared__ ushort vt[32][360];      // V transposed: vt[d][token]
  __shared__ ushort pl[4][16][360];   // per-wave P tile (16 q-rows x 352 keys)
  const int wh = blockIdx.x;
  const int win = wh >> 2, head = wh & 3;
  const int tid = threadIdx.x, lane = tid & 63, wave = tid >> 6;
  // stage V transposed (all 4 waves cooperate), zero padding tokens
  for (int t = tid; t < 352; t += 256) {
    if (t < NTOK) {
      ushort tmp[32];
      const ushort* vr = V + ((size_t)wh * NTOK + t) * HD;
      *reinterpret_cast<int4*>(&tmp[0])  = *reinterpret_cast<const int4*>(vr);
      *reinterpret_cast<int4*>(&tmp[8])  = *reinterpret_cast<const int4*>(vr + 8);
      *reinterpret_cast<int4*>(&tmp[16]) = *reinterpret_cast<const int4*>(vr + 16);
      *reinterpret_cast<int4*>(&tmp[24]) = *reinterpret_cast<const int4*>(vr + 24);
      #pragma unroll
      for (int d = 0; d < 32; ++d) vt[d][t] = tmp[d];
    } else {
      #pragma unroll
      for (int d = 0; d < 32; ++d) vt[d][t] = 0;
    }
  }
  __syncthreads();
  const int lr = lane & 15, kb0 = (lane >> 4) * 8;
  for (int mt = wave; mt < NT; mt += 4) {
    int qrow = mt * 16 + lr; if (qrow > 342) qrow = 342;   // clamp pad rows
    bfv8 aq = *reinterpret_cast<const bfv8*>(Q + ((size_t)wh * NTOK + qrow) * HD + kb0);
    const f32x4* bR = biasr + ((size_t)(head * NT + mt) * NT) * 64 + lane;
    f32x4 s[NT];
    #pragma unroll
    for (int nt = 0; nt < NT; ++nt) {
      int krow = nt * 16 + lr; if (krow > 342) krow = 342;
      bfv8 bk = *reinterpret_cast<const bfv8*>(K + ((size_t)wh * NTOK + krow) * HD + kb0);
      s[nt] = MFMA16(aq, bk, bR[nt * 64]);   // C operand = scaled-out bias (+mask)
    }
    // softmax over keys (row = mt*16 + (lane>>4)*4 + r, col = nt*16 + (lane&15))
    float mx[4] = {-3e38f, -3e38f, -3e38f, -3e38f};
    #pragma unroll
    for (int nt = 0; nt < NT; ++nt)
      #pragma unroll
      for (int r = 0; r < 4; ++r) mx[r] = fmaxf(mx[r], s[nt][r]);
    #pragma unroll
    for (int r = 0; r < 4; ++r) {
      #pragma unroll
      for (int off = 1; off < 16; off <<= 1) mx[r] = fmaxf(mx[r], __shfl_xor(mx[r], off));
    }
    float sm[4] = {0.f, 0.f, 0.f, 0.f};
    const int key = lane & 15;
    #pragma unroll
    for (int nt = 0; nt < NT; ++nt) {
      int kcol = nt * 16 + key;
      #pragma unroll
      for (int r = 0; r < 4; ++r) {
        float p = __expf(s[nt][r] - mx[r]);
        sm[r] += p;
        pl[wave][(lane >> 4) * 4 + r][kcol] = f2b(p);   // unnormalized
      }
    }
    #pragma unroll
    for (int r = 0; r < 4; ++r) {
      #pragma unroll
      for (int off = 1; off < 16; off <<= 1) sm[r] += __shfl_xor(sm[r], off);
    }
    float inv[4];
    #pragma unroll
    for (int r = 0; r < 4; ++r) inv[r] = 1.0f / sm[r];
    // PV transposed: O^T[d][q] = sum_k V^T[d][k] * P[q][k]  (A = vt, B = pl)
    f32x4 o0 = {}, o1 = {};
    #pragma unroll
    for (int kt = 0; kt < 11; ++kt) {
      bfv8 bp  = *reinterpret_cast<const bfv8*>(&pl[wave][lr][kt * 32 + kb0]);
      bfv8 av0 = *reinterpret_cast<const bfv8*>(&vt[lr][kt * 32 + kb0]);
      bfv8 av1 = *reinterpret_cast<const bfv8*>(&vt[16 + lr][kt * 32 + kb0]);
      o0 = MFMA16(av0, bp, o0);
      o1 = MFMA16(av1, bp, o1);
    }
    // lane's column q = mt*16 + (lane&15); rows d = (lane>>4)*4 + r (o0), +16 (o1)
    int qcol = lane & 15;
    int srcl = (qcol >> 2) << 4;
    float i0 = __shfl(inv[0], srcl), i1 = __shfl(inv[1], srcl);
    float i2 = __shfl(inv[2], srcl), i3 = __shfl(inv[3], srcl);
    float invq = (qcol & 2) ? ((qcol & 1) ? i3 : i2) : ((qcol & 1) ? i1 : i0);
    int q = mt * 16 + qcol;
    if (q < NTOK) {
      int dbase = (lane >> 4) * 4;
      ushort4 r0, r1;
      r0.x = f2b(o0[0] * invq); r0.y = f2b(o0[1] * invq);
      r0.z = f2b(o0[2] * invq); r0.w = f2b(o0[3] * invq);
      r1.x = f2b(o1[0] * invq); r1.y = f2b(o1[1] * invq);
      r1.z = f2b(o1[2] * invq); r1.w = f2b(o1[3] * invq);
      ushort* ob = out + (size_t)(win * NTOK + q) * C + head * HD;
      *reinterpret_cast<ushort4*>(ob + dbase)      = r0;
      *reinterpret_cast<ushort4*>(ob + 16 + dbase) = r1;
    }
  }
}

// ---------------- launcher ----------------
extern "C" void kernel_launch(void* const* d_in, const int* in_sizes, int n_in,
                              void* d_out, int out_size, void* d_ws, size_t ws_size,
                              hipStream_t stream) {
  const float* x     = (const float*)d_in[0];
  const float* n1w   = (const float*)d_in[1];
  const float* n1b   = (const float*)d_in[2];
  const float* qkvw  = (const float*)d_in[3];
  const float* qkvb  = (const float*)d_in[4];
  const float* rpb   = (const float*)d_in[5];
  const float* projw = (const float*)d_in[6];
  const float* projb = (const float*)d_in[7];
  const float* n2w   = (const float*)d_in[8];
  const float* n2b   = (const float*)d_in[9];
  const float* w1    = (const float*)d_in[10];
  const float* b1    = (const float*)d_in[11];
  const float* w2    = (const float*)d_in[12];
  const float* b2    = (const float*)d_in[13];
  const int*   rel   = (const int*)d_in[14];

  char* ws = (char*)d_ws;
  constexpr size_t SZ_ACT  = (size_t)ROWS * C * 2;              // 11,239,424 (bf16 activations)
  constexpr size_t SZ_BIAS = (size_t)4 * NT * NT * 64 * 16;     // 1,982,464 (reordered f32x4)

  ushort* lnbuf  = (ushort*)(ws);                           // LN1 out, later LN2 out
  ushort* Qb     = (ushort*)(ws + SZ_ACT);
  ushort* Kb     = (ushort*)(ws + 2 * SZ_ACT);
  ushort* Vb     = (ushort*)(ws + 3 * SZ_ACT);
  f32x4*  biasr  = (f32x4*)(ws + 4 * SZ_ACT);
  size_t off_att = (4 * SZ_ACT + SZ_BIAS + 255) & ~(size_t)255;
  ushort* attout = (ushort*)(ws + off_att);
  ushort* h1     = Qb;                                      // overlay Qb..attout (dead by MLP1)
  size_t off_y   = off_att + SZ_ACT;
  float*  y      = (float*)(ws + off_y);
  size_t off_w   = off_y + (size_t)ROWS * C * 4;
  ushort* wqkv   = (ushort*)(ws + off_w);
  ushort* wproj  = (ushort*)(ws + off_w + 98304);
  ushort* wm1    = (ushort*)(ws + off_w + 131072);
  ushort* wm2    = (ushort*)(ws + off_w + 262144);
  float*  outp   = (float*)d_out;

  cvt_kernel<<<768, 256, 0, stream>>>(qkvw, projw, w1, w2, wqkv, wproj, wm1, wm2);
  bias_kernel<<<(4 * NT * NT * 64 + 255) / 256, 256, 0, stream>>>(rel, rpb, (float4*)biasr);
  ln_kernel<true><<<ROWS / 4, 256, 0, stream>>>(x, n1w, n1b, lnbuf);
  gemm_kernel<128, 0><<<dim3(ROWS / 64, 6), 256, 0, stream>>>(lnbuf, wqkv, qkvb, nullptr, Qb, Kb, Vb, nullptr);
  attn_kernel<<<512, 256, 0, stream>>>(Qb, Kb, Vb, biasr, attout);
  gemm_kernel<128, 1><<<dim3(ROWS / 64, 2), 256, 0, stream>>>(attout, wproj, projb, x, nullptr, nullptr, nullptr, y);
  ln_kernel<false><<<ROWS / 4, 256, 0, stream>>>(y, n2w, n2b, lnbuf);
  gemm_kernel<128, 2><<<dim3(ROWS / 64, 8), 256, 0, stream>>>(lnbuf, wm1, b1, nullptr, h1, nullptr, nullptr, nullptr);
  gemm_kernel<512, 3><<<dim3(ROWS / 64, 2), 256, 0, stream>>>(h1, wm2, b2, y, nullptr, nullptr, nullptr, outp);
}

// Round 5
// 140.383 us; speedup vs baseline: 4.4280x; 1.1035x over previous
//
#include <hip/hip_runtime.h>

typedef __bf16 bfv8 __attribute__((ext_vector_type(8)));
typedef float f32x4 __attribute__((ext_vector_type(4)));
#define MFMA16(a,b,c) __builtin_amdgcn_mfma_f32_16x16x32_bf16(a,b,c,0,0,0)

constexpr int C      = 128;
constexpr int HD     = 32;
constexpr int NTOK   = 343;     // tokens per window (7^3)
constexpr int ROWS   = 43904;   // B*H*W*D = 2*28^3
constexpr int HIDDEN = 512;
constexpr float SCALE = 0.17677669529663687f;  // 32^-0.5
constexpr float EPS   = 1e-5f;
constexpr int NT = 22;          // 16-row tiles per window (ceil(343/16))

static __device__ __forceinline__ float b2f(ushort u) {
  union { unsigned int i; float f; } x; x.i = ((unsigned int)u) << 16; return x.f;
}
static __device__ __forceinline__ ushort f2b(float f) {
  union { float f; unsigned int i; } x; x.f = f;
  unsigned int r = x.i + 0x7fffu + ((x.i >> 16) & 1u);
  return (ushort)(r >> 16);
}

// dest row (window layout) -> source row (original layout), includes roll by 3
static __device__ __forceinline__ int perm_row(int row) {
  int win = row / NTOK, tok = row - win * NTOK;
  int bb = win >> 6, wi = win & 63;
  int a  = wi >> 4, w2 = (wi >> 2) & 3, c2 = wi & 3;
  int t1 = tok / 49, rem = tok - t1 * 49;
  int t2 = rem / 7,  t3 = rem - t2 * 7;
  int gh = a * 7 + t1 + 3;  if (gh >= 28) gh -= 28;
  int gw = w2 * 7 + t2 + 3; if (gw >= 28) gw -= 28;
  int gd = c2 * 7 + t3 + 3; if (gd >= 28) gd -= 28;
  return bb * 21952 + gh * 784 + gw * 28 + gd;
}

// ---------------- f32 -> bf16 weight conversion ----------------
__global__ __launch_bounds__(256) void cvt_kernel(const float* __restrict__ s0,
                                                  const float* __restrict__ s1,
                                                  const float* __restrict__ s2,
                                                  const float* __restrict__ s3,
                                                  ushort* __restrict__ d0,
                                                  ushort* __restrict__ d1,
                                                  ushort* __restrict__ d2,
                                                  ushort* __restrict__ d3) {
  int t = blockIdx.x * 256 + threadIdx.x;
  if (t < 49152)       d0[t]          = f2b(s0[t]);
  else if (t < 65536)  d1[t - 49152]  = f2b(s1[t - 49152]);
  else if (t < 131072) d2[t - 65536]  = f2b(s2[t - 65536]);
  else                 d3[t - 131072] = f2b(s3[t - 131072]);
}

// ------- bias reordered into MFMA C-fragment order, mask baked in -------
// biasr[((head*NT + mt)*NT + nt)*64 + lane] = float4 (r = 0..3)
// element (q = mt*16 + (lane>>4)*4 + r, k = nt*16 + (lane&15)); pad -> -3e38
__global__ __launch_bounds__(256) void bias_kernel(const int* __restrict__ rel,
                                                   const float* __restrict__ tab,
                                                   float4* __restrict__ biasr) {
  int t = blockIdx.x * 256 + threadIdx.x;
  if (t >= 4 * NT * NT * 64) return;
  int lane = t & 63;
  int nt   = (t >> 6) % NT;
  int mt   = ((t >> 6) / NT) % NT;
  int head = t / (64 * NT * NT);
  int k  = nt * 16 + (lane & 15);
  int qb = mt * 16 + (lane >> 4) * 4;
  float vv[4];
  #pragma unroll
  for (int r = 0; r < 4; ++r) {
    int q = qb + r;
    if (q < NTOK && k < NTOK) {
      int idx = rel[q * NTOK + k];
      vv[r] = tab[idx * 4 + head];
    } else {
      vv[r] = -3e38f;
    }
  }
  biasr[t] = make_float4(vv[0], vv[1], vv[2], vv[3]);
}

// ---------------- LayerNorm (optionally with roll+window permutation), f32 in -> bf16 out ----
template<bool PERM>
__global__ __launch_bounds__(256) void ln_kernel(const float* __restrict__ in,
                                                 const float* __restrict__ w,
                                                 const float* __restrict__ b,
                                                 ushort* __restrict__ out) {
  int wid = threadIdx.x >> 6, lane = threadIdx.x & 63;
  int row = blockIdx.x * 4 + wid;
  int src = PERM ? perm_row(row) : row;
  float2 v = *reinterpret_cast<const float2*>(in + (size_t)src * C + lane * 2);
  float s = v.x + v.y, q = v.x * v.x + v.y * v.y;
  #pragma unroll
  for (int off = 32; off; off >>= 1) { s += __shfl_xor(s, off); q += __shfl_xor(q, off); }
  float mu = s * (1.0f / 128.0f);
  float var = q * (1.0f / 128.0f) - mu * mu;
  float rs = rsqrtf(var + EPS);
  int c = lane * 2;
  ushort2 ov;
  ov.x = f2b((v.x - mu) * rs * w[c]     + b[c]);
  ov.y = f2b((v.y - mu) * rs * w[c + 1] + b[c + 1]);
  *reinterpret_cast<ushort2*>(out + (size_t)row * C + c) = ov;
}

// ---------------- 128x128-tile bf16 MFMA GEMM with fused epilogues ----------------
// acc = A[128 x K] * W[128 x K]^T  (+bias, +epilogue); 4 waves, each 64x64
// EPI 0: QKV scatter (bf16, Q pre-scaled)  1: proj + residual(f32 x) -> f32 y, un-permute
// EPI 2: gelu -> bf16 h1                   3: mlp2 + residual(f32 y) -> f32 out
template<int KTOT, int EPI>
__global__ __launch_bounds__(256) void gemm_kernel(const ushort* __restrict__ A,
                                                   const ushort* __restrict__ W,
                                                   const float* __restrict__ bias,
                                                   const float* __restrict__ X,
                                                   ushort* __restrict__ O0,
                                                   ushort* __restrict__ O1,
                                                   ushort* __restrict__ O2,
                                                   float* __restrict__ OF) {
  __shared__ ushort Al[128][136];
  __shared__ ushort Bl[128][136];
  const int m0 = blockIdx.x * 128, n0 = blockIdx.y * 128;
  const int tid = threadIdx.x, lane = tid & 63, wid = tid >> 6;
  const int wr = wid >> 1, wc = wid & 1;
  const int lr = lane & 15, kb0 = (lane >> 4) * 8;
  const int sr = tid >> 4, sc = (tid & 15) * 8;
  f32x4 acc[4][4] = {};
  for (int kc = 0; kc < KTOT; kc += 128) {
    #pragma unroll
    for (int p = 0; p < 8; ++p) {
      int row = p * 16 + sr;
      *reinterpret_cast<int4*>(&Al[row][sc]) =
          *reinterpret_cast<const int4*>(&A[(size_t)(m0 + row) * KTOT + kc + sc]);
      *reinterpret_cast<int4*>(&Bl[row][sc]) =
          *reinterpret_cast<const int4*>(&W[(size_t)(n0 + row) * KTOT + kc + sc]);
    }
    __syncthreads();
    #pragma unroll
    for (int kk = 0; kk < 4; ++kk) {
      int kb = kk * 32 + kb0;
      bfv8 a[4], b[4];
      #pragma unroll
      for (int m = 0; m < 4; ++m) a[m] = *reinterpret_cast<const bfv8*>(&Al[wr * 64 + m * 16 + lr][kb]);
      #pragma unroll
      for (int n = 0; n < 4; ++n) b[n] = *reinterpret_cast<const bfv8*>(&Bl[wc * 64 + n * 16 + lr][kb]);
      #pragma unroll
      for (int m = 0; m < 4; ++m)
        #pragma unroll
        for (int n = 0; n < 4; ++n)
          acc[m][n] = MFMA16(a[m], b[n], acc[m][n]);
    }
    __syncthreads();
  }
  #pragma unroll
  for (int m = 0; m < 4; ++m)
    #pragma unroll
    for (int n = 0; n < 4; ++n)
      #pragma unroll
      for (int r = 0; r < 4; ++r) {
        int gm = m0 + wr * 64 + m * 16 + (lane >> 4) * 4 + r;
        int gn = n0 + wc * 64 + n * 16 + (lane & 15);
        float v = acc[m][n][r] + bias[gn];
        if (EPI == 0) {
          int which = gn >> 7, head = (gn >> 5) & 3, d = gn & 31;
          if (which == 0) v *= SCALE;     // fold attention scale into Q
          int win = gm / NTOK, tok = gm - win * NTOK;
          ushort* dst = (which == 0) ? O0 : (which == 1) ? O1 : O2;
          dst[((win * 4 + head) * NTOK + tok) * HD + d] = f2b(v);
        } else if (EPI == 1) {
          int orig = perm_row(gm);
          OF[(size_t)orig * C + gn] = v + X[(size_t)orig * C + gn];
        } else if (EPI == 2) {
          float g = 0.5f * v * (1.0f + erff(v * 0.70710678118654752f));
          O0[(size_t)gm * HIDDEN + gn] = f2b(g);
        } else {
          OF[(size_t)gm * C + gn] = v + X[(size_t)gm * C + gn];
        }
      }
}

// ---------------- windowed attention: one block (8 waves) per (window, head) ----------------
// bias pre-reordered as MFMA C operand (mask baked in); Q pre-scaled; no-max softmax
// (S bounded, pads exp(-3e38)=0); per-nt fused exp keeps VGPR low; P split in two
// k-phases (192 + 160 keys) to shrink LDS; PV transposed so outputs pack as ushort4.
__global__ __launch_bounds__(512) void attn_kernel(const ushort* __restrict__ Q,
                                                   const ushort* __restrict__ K,
                                                   const ushort* __restrict__ V,
                                                   const f32x4* __restrict__ biasr,
                                                   ushort* __restrict__ out) {
  __shared__ ushort vt[32][360];       // V transposed: vt[d][token]
  __shared__ ushort pl[8][16][204];    // per-wave P phase-tile (16 q-rows x <=192 keys)
  const int wh = blockIdx.x;
  const int win = wh >> 2, head = wh & 3;
  const int tid = threadIdx.x, lane = tid & 63, wave = tid >> 6;
  // stage V transposed (single pass, 512 threads), zero padding tokens
  if (tid < 352) {
    int t = tid;
    if (t < NTOK) {
      ushort tmp[32];
      const ushort* vr = V + ((size_t)wh * NTOK + t) * HD;
      *reinterpret_cast<int4*>(&tmp[0])  = *reinterpret_cast<const int4*>(vr);
      *reinterpret_cast<int4*>(&tmp[8])  = *reinterpret_cast<const int4*>(vr + 8);
      *reinterpret_cast<int4*>(&tmp[16]) = *reinterpret_cast<const int4*>(vr + 16);
      *reinterpret_cast<int4*>(&tmp[24]) = *reinterpret_cast<const int4*>(vr + 24);
      #pragma unroll
      for (int d = 0; d < 32; ++d) vt[d][t] = tmp[d];
    } else {
      #pragma unroll
      for (int d = 0; d < 32; ++d) vt[d][t] = 0;
    }
  }
  __syncthreads();
  const int lr = lane & 15, kb0 = (lane >> 4) * 8;
  const int key = lane & 15, qr4 = (lane >> 4) * 4;
  for (int mt = wave; mt < NT; mt += 8) {
    int qrow = mt * 16 + lr; if (qrow > 342) qrow = 342;   // clamp pad rows
    bfv8 aq = *reinterpret_cast<const bfv8*>(Q + ((size_t)wh * NTOK + qrow) * HD + kb0);
    const f32x4* bR = biasr + ((size_t)(head * NT + mt) * NT) * 64 + lane;
    float sm[4] = {0.f, 0.f, 0.f, 0.f};
    f32x4 o0 = {}, o1 = {};
    // ---- phase 0: keys 0..191 (nt 0..11) ----
    #pragma unroll
    for (int nt = 0; nt < 12; ++nt) {
      int krow = nt * 16 + lr;
      bfv8 bk = *reinterpret_cast<const bfv8*>(K + ((size_t)wh * NTOK + krow) * HD + kb0);
      f32x4 s = MFMA16(aq, bk, bR[nt * 64]);    // C operand = bias (+mask)
      int kcol = nt * 16 + key;
      #pragma unroll
      for (int r = 0; r < 4; ++r) {
        float p = __expf(s[r]);
        sm[r] += p;
        pl[wave][qr4 + r][kcol] = f2b(p);       // unnormalized
      }
    }
    #pragma unroll
    for (int kt = 0; kt < 6; ++kt) {
      bfv8 bp  = *reinterpret_cast<const bfv8*>(&pl[wave][lr][kt * 32 + kb0]);
      bfv8 av0 = *reinterpret_cast<const bfv8*>(&vt[lr][kt * 32 + kb0]);
      bfv8 av1 = *reinterpret_cast<const bfv8*>(&vt[16 + lr][kt * 32 + kb0]);
      o0 = MFMA16(av0, bp, o0);
      o1 = MFMA16(av1, bp, o1);
    }
    // ---- phase 1: keys 192..351 (nt 12..21) ----
    #pragma unroll
    for (int nt = 12; nt < NT; ++nt) {
      int krow = nt * 16 + lr; if (krow > 342) krow = 342;
      bfv8 bk = *reinterpret_cast<const bfv8*>(K + ((size_t)wh * NTOK + krow) * HD + kb0);
      f32x4 s = MFMA16(aq, bk, bR[nt * 64]);
      int kcol = (nt - 12) * 16 + key;
      #pragma unroll
      for (int r = 0; r < 4; ++r) {
        float p = __expf(s[r]);
        sm[r] += p;
        pl[wave][qr4 + r][kcol] = f2b(p);
      }
    }
    #pragma unroll
    for (int kt = 0; kt < 5; ++kt) {
      bfv8 bp  = *reinterpret_cast<const bfv8*>(&pl[wave][lr][kt * 32 + kb0]);
      bfv8 av0 = *reinterpret_cast<const bfv8*>(&vt[lr][192 + kt * 32 + kb0]);
      bfv8 av1 = *reinterpret_cast<const bfv8*>(&vt[16 + lr][192 + kt * 32 + kb0]);
      o0 = MFMA16(av0, bp, o0);
      o1 = MFMA16(av1, bp, o1);
    }
    // row sums across the 16-lane groups
    #pragma unroll
    for (int r = 0; r < 4; ++r) {
      #pragma unroll
      for (int off = 1; off < 16; off <<= 1) sm[r] += __shfl_xor(sm[r], off);
    }
    float inv[4];
    #pragma unroll
    for (int r = 0; r < 4; ++r) inv[r] = 1.0f / sm[r];
    // lane's output column q = mt*16 + (lane&15); rows d = (lane>>4)*4 + r (o0), +16 (o1)
    int qcol = lane & 15;
    int srcl = (qcol >> 2) << 4;
    float i0 = __shfl(inv[0], srcl), i1 = __shfl(inv[1], srcl);
    float i2 = __shfl(inv[2], srcl), i3 = __shfl(inv[3], srcl);
    float invq = (qcol & 2) ? ((qcol & 1) ? i3 : i2) : ((qcol & 1) ? i1 : i0);
    int q = mt * 16 + qcol;
    if (q < NTOK) {
      int dbase = qr4;
      ushort4 r0, r1;
      r0.x = f2b(o0[0] * invq); r0.y = f2b(o0[1] * invq);
      r0.z = f2b(o0[2] * invq); r0.w = f2b(o0[3] * invq);
      r1.x = f2b(o1[0] * invq); r1.y = f2b(o1[1] * invq);
      r1.z = f2b(o1[2] * invq); r1.w = f2b(o1[3] * invq);
      ushort* ob = out + (size_t)(win * NTOK + q) * C + head * HD;
      *reinterpret_cast<ushort4*>(ob + dbase)      = r0;
      *reinterpret_cast<ushort4*>(ob + 16 + dbase) = r1;
    }
  }
}

// ---------------- launcher ----------------
extern "C" void kernel_launch(void* const* d_in, const int* in_sizes, int n_in,
                              void* d_out, int out_size, void* d_ws, size_t ws_size,
                              hipStream_t stream) {
  const float* x     = (const float*)d_in[0];
  const float* n1w   = (const float*)d_in[1];
  const float* n1b   = (const float*)d_in[2];
  const float* qkvw  = (const float*)d_in[3];
  const float* qkvb  = (const float*)d_in[4];
  const float* rpb   = (const float*)d_in[5];
  const float* projw = (const float*)d_in[6];
  const float* projb = (const float*)d_in[7];
  const float* n2w   = (const float*)d_in[8];
  const float* n2b   = (const float*)d_in[9];
  const float* w1    = (const float*)d_in[10];
  const float* b1    = (const float*)d_in[11];
  const float* w2    = (const float*)d_in[12];
  const float* b2    = (const float*)d_in[13];
  const int*   rel   = (const int*)d_in[14];

  char* ws = (char*)d_ws;
  constexpr size_t SZ_ACT  = (size_t)ROWS * C * 2;              // 11,239,424 (bf16 activations)
  constexpr size_t SZ_BIAS = (size_t)4 * NT * NT * 64 * 16;     // 1,982,464 (reordered f32x4)

  ushort* lnbuf  = (ushort*)(ws);                           // LN1 out, later LN2 out
  ushort* Qb     = (ushort*)(ws + SZ_ACT);
  ushort* Kb     = (ushort*)(ws + 2 * SZ_ACT);
  ushort* Vb     = (ushort*)(ws + 3 * SZ_ACT);
  f32x4*  biasr  = (f32x4*)(ws + 4 * SZ_ACT);
  size_t off_att = (4 * SZ_ACT + SZ_BIAS + 255) & ~(size_t)255;
  ushort* attout = (ushort*)(ws + off_att);
  ushort* h1     = Qb;                                      // overlay Qb..attout (dead by MLP1)
  size_t off_y   = off_att + SZ_ACT;
  float*  y      = (float*)(ws + off_y);
  size_t off_w   = off_y + (size_t)ROWS * C * 4;
  ushort* wqkv   = (ushort*)(ws + off_w);
  ushort* wproj  = (ushort*)(ws + off_w + 98304);
  ushort* wm1    = (ushort*)(ws + off_w + 131072);
  ushort* wm2    = (ushort*)(ws + off_w + 262144);
  float*  outp   = (float*)d_out;

  cvt_kernel<<<768, 256, 0, stream>>>(qkvw, projw, w1, w2, wqkv, wproj, wm1, wm2);
  bias_kernel<<<(4 * NT * NT * 64 + 255) / 256, 256, 0, stream>>>(rel, rpb, (float4*)biasr);
  ln_kernel<true><<<ROWS / 4, 256, 0, stream>>>(x, n1w, n1b, lnbuf);
  gemm_kernel<128, 0><<<dim3(343, 3), 256, 0, stream>>>(lnbuf, wqkv, qkvb, nullptr, Qb, Kb, Vb, nullptr);
  attn_kernel<<<512, 512, 0, stream>>>(Qb, Kb, Vb, biasr, attout);
  gemm_kernel<128, 1><<<dim3(343, 1), 256, 0, stream>>>(attout, wproj, projb, x, nullptr, nullptr, nullptr, y);
  ln_kernel<false><<<ROWS / 4, 256, 0, stream>>>(y, n2w, n2b, lnbuf);
  gemm_kernel<128, 2><<<dim3(343, 4), 256, 0, stream>>>(lnbuf, wm1, b1, nullptr, h1, nullptr, nullptr, nullptr);
  gemm_kernel<512, 3><<<dim3(343, 1), 256, 0, stream>>>(h1, wm2, b2, y, nullptr, nullptr, nullptr, outp);
}

// Round 6
// 137.615 us; speedup vs baseline: 4.5170x; 1.0201x over previous
//
#include <hip/hip_runtime.h>

typedef __bf16 bfv8 __attribute__((ext_vector_type(8)));
typedef float f32x4 __attribute__((ext_vector_type(4)));
#define MFMA16(a,b,c) __builtin_amdgcn_mfma_f32_16x16x32_bf16(a,b,c,0,0,0)

constexpr int C      = 128;
constexpr int HD     = 32;
constexpr int NTOK   = 343;     // tokens per window (7^3)
constexpr int ROWS   = 43904;   // B*H*W*D = 2*28^3
constexpr int HIDDEN = 512;
constexpr float SCALE = 0.17677669529663687f;  // 32^-0.5
constexpr float EPS   = 1e-5f;
constexpr int NT = 22;          // 16-row tiles per window (ceil(343/16))

static __device__ __forceinline__ float b2f(ushort u) {
  union { unsigned int i; float f; } x; x.i = ((unsigned int)u) << 16; return x.f;
}
static __device__ __forceinline__ ushort f2b(float f) {
  union { float f; unsigned int i; } x; x.f = f;
  unsigned int r = x.i + 0x7fffu + ((x.i >> 16) & 1u);
  return (ushort)(r >> 16);
}

// dest row (window layout) -> source row (original layout), includes roll by 3
static __device__ __forceinline__ int perm_row(int row) {
  int win = row / NTOK, tok = row - win * NTOK;
  int bb = win >> 6, wi = win & 63;
  int a  = wi >> 4, w2 = (wi >> 2) & 3, c2 = wi & 3;
  int t1 = tok / 49, rem = tok - t1 * 49;
  int t2 = rem / 7,  t3 = rem - t2 * 7;
  int gh = a * 7 + t1 + 3;  if (gh >= 28) gh -= 28;
  int gw = w2 * 7 + t2 + 3; if (gw >= 28) gw -= 28;
  int gd = c2 * 7 + t3 + 3; if (gd >= 28) gd -= 28;
  return bb * 21952 + gh * 784 + gw * 28 + gd;
}

// ---------------- f32 -> bf16 weight conversion ----------------
__global__ __launch_bounds__(256) void cvt_kernel(const float* __restrict__ s0,
                                                  const float* __restrict__ s1,
                                                  const float* __restrict__ s2,
                                                  const float* __restrict__ s3,
                                                  ushort* __restrict__ d0,
                                                  ushort* __restrict__ d1,
                                                  ushort* __restrict__ d2,
                                                  ushort* __restrict__ d3) {
  int t = blockIdx.x * 256 + threadIdx.x;
  if (t < 49152)       d0[t]          = f2b(s0[t]);
  else if (t < 65536)  d1[t - 49152]  = f2b(s1[t - 49152]);
  else if (t < 131072) d2[t - 65536]  = f2b(s2[t - 65536]);
  else                 d3[t - 131072] = f2b(s3[t - 131072]);
}

// ------- bias reordered into MFMA C-fragment order, mask baked in -------
// biasr[((head*NT + mt)*NT + nt)*64 + lane] = float4 (r = 0..3)
// element (q = mt*16 + (lane>>4)*4 + r, k = nt*16 + (lane&15)); pad -> -3e38
__global__ __launch_bounds__(256) void bias_kernel(const int* __restrict__ rel,
                                                   const float* __restrict__ tab,
                                                   float4* __restrict__ biasr) {
  int t = blockIdx.x * 256 + threadIdx.x;
  if (t >= 4 * NT * NT * 64) return;
  int lane = t & 63;
  int nt   = (t >> 6) % NT;
  int mt   = ((t >> 6) / NT) % NT;
  int head = t / (64 * NT * NT);
  int k  = nt * 16 + (lane & 15);
  int qb = mt * 16 + (lane >> 4) * 4;
  float vv[4];
  #pragma unroll
  for (int r = 0; r < 4; ++r) {
    int q = qb + r;
    if (q < NTOK && k < NTOK) {
      int idx = rel[q * NTOK + k];
      vv[r] = tab[idx * 4 + head];
    } else {
      vv[r] = -3e38f;
    }
  }
  biasr[t] = make_float4(vv[0], vv[1], vv[2], vv[3]);
}

// ---------------- LayerNorm with roll+window permutation, f32 in -> bf16 out ----
template<bool PERM>
__global__ __launch_bounds__(256) void ln_kernel(const float* __restrict__ in,
                                                 const float* __restrict__ w,
                                                 const float* __restrict__ b,
                                                 ushort* __restrict__ out) {
  int wid = threadIdx.x >> 6, lane = threadIdx.x & 63;
  int row = blockIdx.x * 4 + wid;
  int src = PERM ? perm_row(row) : row;
  float2 v = *reinterpret_cast<const float2*>(in + (size_t)src * C + lane * 2);
  float s = v.x + v.y, q = v.x * v.x + v.y * v.y;
  #pragma unroll
  for (int off = 32; off; off >>= 1) { s += __shfl_xor(s, off); q += __shfl_xor(q, off); }
  float mu = s * (1.0f / 128.0f);
  float var = q * (1.0f / 128.0f) - mu * mu;
  float rs = rsqrtf(var + EPS);
  int c = lane * 2;
  ushort2 ov;
  ov.x = f2b((v.x - mu) * rs * w[c]     + b[c]);
  ov.y = f2b((v.y - mu) * rs * w[c + 1] + b[c + 1]);
  *reinterpret_cast<ushort2*>(out + (size_t)row * C + c) = ov;
}

// ---------------- 128x128-tile bf16 MFMA GEMM with fused epilogues ----------------
// acc = A[128 x K] * W[128 x K]^T  (+bias, +epilogue); 4 waves, each 64x64
// EPI 0: QKV scatter (bf16, Q pre-scaled)  1: proj + residual(f32 x) -> f32 y, un-permute
template<int KTOT, int EPI>
__global__ __launch_bounds__(256) void gemm_kernel(const ushort* __restrict__ A,
                                                   const ushort* __restrict__ W,
                                                   const float* __restrict__ bias,
                                                   const float* __restrict__ X,
                                                   ushort* __restrict__ O0,
                                                   ushort* __restrict__ O1,
                                                   ushort* __restrict__ O2,
                                                   float* __restrict__ OF) {
  __shared__ ushort Al[128][136];
  __shared__ ushort Bl[128][136];
  const int m0 = blockIdx.x * 128, n0 = blockIdx.y * 128;
  const int tid = threadIdx.x, lane = tid & 63, wid = tid >> 6;
  const int wr = wid >> 1, wc = wid & 1;
  const int lr = lane & 15, kb0 = (lane >> 4) * 8;
  const int sr = tid >> 4, sc = (tid & 15) * 8;
  f32x4 acc[4][4] = {};
  for (int kc = 0; kc < KTOT; kc += 128) {
    #pragma unroll
    for (int p = 0; p < 8; ++p) {
      int row = p * 16 + sr;
      *reinterpret_cast<int4*>(&Al[row][sc]) =
          *reinterpret_cast<const int4*>(&A[(size_t)(m0 + row) * KTOT + kc + sc]);
      *reinterpret_cast<int4*>(&Bl[row][sc]) =
          *reinterpret_cast<const int4*>(&W[(size_t)(n0 + row) * KTOT + kc + sc]);
    }
    __syncthreads();
    #pragma unroll
    for (int kk = 0; kk < 4; ++kk) {
      int kb = kk * 32 + kb0;
      bfv8 a[4], b[4];
      #pragma unroll
      for (int m = 0; m < 4; ++m) a[m] = *reinterpret_cast<const bfv8*>(&Al[wr * 64 + m * 16 + lr][kb]);
      #pragma unroll
      for (int n = 0; n < 4; ++n) b[n] = *reinterpret_cast<const bfv8*>(&Bl[wc * 64 + n * 16 + lr][kb]);
      #pragma unroll
      for (int m = 0; m < 4; ++m)
        #pragma unroll
        for (int n = 0; n < 4; ++n)
          acc[m][n] = MFMA16(a[m], b[n], acc[m][n]);
    }
    __syncthreads();
  }
  #pragma unroll
  for (int m = 0; m < 4; ++m)
    #pragma unroll
    for (int n = 0; n < 4; ++n)
      #pragma unroll
      for (int r = 0; r < 4; ++r) {
        int gm = m0 + wr * 64 + m * 16 + (lane >> 4) * 4 + r;
        int gn = n0 + wc * 64 + n * 16 + (lane & 15);
        float v = acc[m][n][r] + bias[gn];
        if (EPI == 0) {
          int which = gn >> 7, head = (gn >> 5) & 3, d = gn & 31;
          if (which == 0) v *= SCALE;     // fold attention scale into Q
          int win = gm / NTOK, tok = gm - win * NTOK;
          ushort* dst = (which == 0) ? O0 : (which == 1) ? O1 : O2;
          dst[((win * 4 + head) * NTOK + tok) * HD + d] = f2b(v);
        } else {
          int orig = perm_row(gm);
          OF[(size_t)orig * C + gn] = v + X[(size_t)orig * C + gn];
        }
      }
}

// ---------------- fused LN2 + MLP1 + gelu + MLP2 + residual ----------------
// One block per 64 rows; 4 waves, each owning 16 rows. h1 never touches HBM:
// per HIDDEN chunk of 128: stage W1c -> MFMA -> gelu -> private per-wave h1 LDS
// -> stage W2c -> MFMA-accumulate. Epilogue adds b2 + y.
__global__ __launch_bounds__(256) void mlp_kernel(const float* __restrict__ y,
                                                  const float* __restrict__ nw,
                                                  const float* __restrict__ nb,
                                                  const ushort* __restrict__ W1,
                                                  const float* __restrict__ b1,
                                                  const ushort* __restrict__ W2,
                                                  const float* __restrict__ b2,
                                                  float* __restrict__ outp) {
  __shared__ ushort Al[64][136];      // LN2 output tile (bf16)
  __shared__ ushort Hl[4][16][136];   // per-wave gelu(h1) chunk
  __shared__ ushort Wl[128][136];     // W1c / W2c, time-multiplexed
  const int m0 = blockIdx.x * 64;
  const int tid = threadIdx.x, lane = tid & 63, wave = tid >> 6;
  // ---- LN2: 8 threads per row, 2 passes over 64 rows ----
  {
    int sub = tid & 7;
    #pragma unroll
    for (int p = 0; p < 2; ++p) {
      int row = p * 32 + (tid >> 3);
      const float* yr = y + (size_t)(m0 + row) * C + sub * 16;
      float4 v0 = *reinterpret_cast<const float4*>(yr);
      float4 v1 = *reinterpret_cast<const float4*>(yr + 4);
      float4 v2 = *reinterpret_cast<const float4*>(yr + 8);
      float4 v3 = *reinterpret_cast<const float4*>(yr + 12);
      float s = v0.x + v0.y + v0.z + v0.w + v1.x + v1.y + v1.z + v1.w
              + v2.x + v2.y + v2.z + v2.w + v3.x + v3.y + v3.z + v3.w;
      float q = v0.x*v0.x + v0.y*v0.y + v0.z*v0.z + v0.w*v0.w
              + v1.x*v1.x + v1.y*v1.y + v1.z*v1.z + v1.w*v1.w
              + v2.x*v2.x + v2.y*v2.y + v2.z*v2.z + v2.w*v2.w
              + v3.x*v3.x + v3.y*v3.y + v3.z*v3.z + v3.w*v3.w;
      #pragma unroll
      for (int off = 1; off < 8; off <<= 1) { s += __shfl_xor(s, off); q += __shfl_xor(q, off); }
      float mu = s * (1.0f / 128.0f);
      float var = q * (1.0f / 128.0f) - mu * mu;
      float rs = rsqrtf(var + EPS);
      int c0 = sub * 16;
      float4 vv[4] = {v0, v1, v2, v3};
      #pragma unroll
      for (int j = 0; j < 4; ++j) {
        int c = c0 + j * 4;
        ushort4 o;
        o.x = f2b((vv[j].x - mu) * rs * nw[c]     + nb[c]);
        o.y = f2b((vv[j].y - mu) * rs * nw[c + 1] + nb[c + 1]);
        o.z = f2b((vv[j].z - mu) * rs * nw[c + 2] + nb[c + 2]);
        o.w = f2b((vv[j].w - mu) * rs * nw[c + 3] + nb[c + 3]);
        *reinterpret_cast<ushort4*>(&Al[row][c]) = o;
      }
    }
  }
  __syncthreads();
  const int lr = lane & 15, kb0 = (lane >> 4) * 8;
  const int key = lane & 15, qr4 = (lane >> 4) * 4;
  const int sr = tid >> 4, sc = (tid & 15) * 8;
  bfv8 af[4];
  #pragma unroll
  for (int kk = 0; kk < 4; ++kk)
    af[kk] = *reinterpret_cast<const bfv8*>(&Al[wave * 16 + lr][kk * 32 + kb0]);
  f32x4 acc[8] = {};
  for (int c = 0; c < 4; ++c) {
    // stage W1 chunk [hidden rows c*128..+128][k 0..128]
    #pragma unroll
    for (int p = 0; p < 8; ++p) {
      int row = p * 16 + sr;
      *reinterpret_cast<int4*>(&Wl[row][sc]) =
          *reinterpret_cast<const int4*>(&W1[(size_t)(c * 128 + row) * 128 + sc]);
    }
    __syncthreads();
    f32x4 hacc[8] = {};
    #pragma unroll
    for (int kk = 0; kk < 4; ++kk) {
      bfv8 a = af[kk];
      #pragma unroll
      for (int n = 0; n < 8; ++n) {
        bfv8 w = *reinterpret_cast<const bfv8*>(&Wl[n * 16 + lr][kk * 32 + kb0]);
        hacc[n] = MFMA16(a, w, hacc[n]);
      }
    }
    #pragma unroll
    for (int n = 0; n < 8; ++n)
      #pragma unroll
      for (int r = 0; r < 4; ++r) {
        float val = hacc[n][r] + b1[c * 128 + n * 16 + key];
        float g = 0.5f * val * (1.0f + erff(val * 0.70710678118654752f));
        Hl[wave][qr4 + r][n * 16 + key] = f2b(g);
      }
    bfv8 hf[4];
    #pragma unroll
    for (int kk = 0; kk < 4; ++kk)
      hf[kk] = *reinterpret_cast<const bfv8*>(&Hl[wave][lr][kk * 32 + kb0]);  // same-wave dep
    __syncthreads();
    // stage W2 chunk [C rows 0..128][k = c*128..+128]
    #pragma unroll
    for (int p = 0; p < 8; ++p) {
      int row = p * 16 + sr;
      *reinterpret_cast<int4*>(&Wl[row][sc]) =
          *reinterpret_cast<const int4*>(&W2[(size_t)row * HIDDEN + c * 128 + sc]);
    }
    __syncthreads();
    #pragma unroll
    for (int kk = 0; kk < 4; ++kk) {
      bfv8 h = hf[kk];
      #pragma unroll
      for (int n = 0; n < 8; ++n) {
        bfv8 w = *reinterpret_cast<const bfv8*>(&Wl[n * 16 + lr][kk * 32 + kb0]);
        acc[n] = MFMA16(h, w, acc[n]);
      }
    }
    __syncthreads();   // Wl reused next chunk
  }
  #pragma unroll
  for (int n = 0; n < 8; ++n)
    #pragma unroll
    for (int r = 0; r < 4; ++r) {
      int gm = m0 + wave * 16 + qr4 + r;
      int gn = n * 16 + key;
      outp[(size_t)gm * C + gn] = acc[n][r] + b2[gn] + y[(size_t)gm * C + gn];
    }
}

// ---------------- windowed attention: one block (8 waves) per (window, head) ----------------
__global__ __launch_bounds__(512) void attn_kernel(const ushort* __restrict__ Q,
                                                   const ushort* __restrict__ K,
                                                   const ushort* __restrict__ V,
                                                   const f32x4* __restrict__ biasr,
                                                   ushort* __restrict__ out) {
  __shared__ ushort vt[32][360];       // V transposed: vt[d][token]
  __shared__ ushort pl[8][16][204];    // per-wave P phase-tile (16 q-rows x <=192 keys)
  const int wh = blockIdx.x;
  const int win = wh >> 2, head = wh & 3;
  const int tid = threadIdx.x, lane = tid & 63, wave = tid >> 6;
  if (tid < 352) {
    int t = tid;
    if (t < NTOK) {
      ushort tmp[32];
      const ushort* vr = V + ((size_t)wh * NTOK + t) * HD;
      *reinterpret_cast<int4*>(&tmp[0])  = *reinterpret_cast<const int4*>(vr);
      *reinterpret_cast<int4*>(&tmp[8])  = *reinterpret_cast<const int4*>(vr + 8);
      *reinterpret_cast<int4*>(&tmp[16]) = *reinterpret_cast<const int4*>(vr + 16);
      *reinterpret_cast<int4*>(&tmp[24]) = *reinterpret_cast<const int4*>(vr + 24);
      #pragma unroll
      for (int d = 0; d < 32; ++d) vt[d][t] = tmp[d];
    } else {
      #pragma unroll
      for (int d = 0; d < 32; ++d) vt[d][t] = 0;
    }
  }
  __syncthreads();
  const int lr = lane & 15, kb0 = (lane >> 4) * 8;
  const int key = lane & 15, qr4 = (lane >> 4) * 4;
  for (int mt = wave; mt < NT; mt += 8) {
    int qrow = mt * 16 + lr; if (qrow > 342) qrow = 342;   // clamp pad rows
    bfv8 aq = *reinterpret_cast<const bfv8*>(Q + ((size_t)wh * NTOK + qrow) * HD + kb0);
    const f32x4* bR = biasr + ((size_t)(head * NT + mt) * NT) * 64 + lane;
    float sm[4] = {0.f, 0.f, 0.f, 0.f};
    f32x4 o0 = {}, o1 = {};
    // ---- phase 0: keys 0..191 (nt 0..11) ----
    #pragma unroll
    for (int nt = 0; nt < 12; ++nt) {
      int krow = nt * 16 + lr;
      bfv8 bk = *reinterpret_cast<const bfv8*>(K + ((size_t)wh * NTOK + krow) * HD + kb0);
      f32x4 s = MFMA16(aq, bk, bR[nt * 64]);    // C operand = bias (+mask)
      int kcol = nt * 16 + key;
      #pragma unroll
      for (int r = 0; r < 4; ++r) {
        float p = __expf(s[r]);
        sm[r] += p;
        pl[wave][qr4 + r][kcol] = f2b(p);       // unnormalized
      }
    }
    #pragma unroll
    for (int kt = 0; kt < 6; ++kt) {
      bfv8 bp  = *reinterpret_cast<const bfv8*>(&pl[wave][lr][kt * 32 + kb0]);
      bfv8 av0 = *reinterpret_cast<const bfv8*>(&vt[lr][kt * 32 + kb0]);
      bfv8 av1 = *reinterpret_cast<const bfv8*>(&vt[16 + lr][kt * 32 + kb0]);
      o0 = MFMA16(av0, bp, o0);
      o1 = MFMA16(av1, bp, o1);
    }
    // ---- phase 1: keys 192..351 (nt 12..21) ----
    #pragma unroll
    for (int nt = 12; nt < NT; ++nt) {
      int krow = nt * 16 + lr; if (krow > 342) krow = 342;
      bfv8 bk = *reinterpret_cast<const bfv8*>(K + ((size_t)wh * NTOK + krow) * HD + kb0);
      f32x4 s = MFMA16(aq, bk, bR[nt * 64]);
      int kcol = (nt - 12) * 16 + key;
      #pragma unroll
      for (int r = 0; r < 4; ++r) {
        float p = __expf(s[r]);
        sm[r] += p;
        pl[wave][qr4 + r][kcol] = f2b(p);
      }
    }
    #pragma unroll
    for (int kt = 0; kt < 5; ++kt) {
      bfv8 bp  = *reinterpret_cast<const bfv8*>(&pl[wave][lr][kt * 32 + kb0]);
      bfv8 av0 = *reinterpret_cast<const bfv8*>(&vt[lr][192 + kt * 32 + kb0]);
      bfv8 av1 = *reinterpret_cast<const bfv8*>(&vt[16 + lr][192 + kt * 32 + kb0]);
      o0 = MFMA16(av0, bp, o0);
      o1 = MFMA16(av1, bp, o1);
    }
    #pragma unroll
    for (int r = 0; r < 4; ++r) {
      #pragma unroll
      for (int off = 1; off < 16; off <<= 1) sm[r] += __shfl_xor(sm[r], off);
    }
    float inv[4];
    #pragma unroll
    for (int r = 0; r < 4; ++r) inv[r] = 1.0f / sm[r];
    int qcol = lane & 15;
    int srcl = (qcol >> 2) << 4;
    float i0 = __shfl(inv[0], srcl), i1 = __shfl(inv[1], srcl);
    float i2 = __shfl(inv[2], srcl), i3 = __shfl(inv[3], srcl);
    float invq = (qcol & 2) ? ((qcol & 1) ? i3 : i2) : ((qcol & 1) ? i1 : i0);
    int q = mt * 16 + qcol;
    if (q < NTOK) {
      int dbase = qr4;
      ushort4 r0, r1;
      r0.x = f2b(o0[0] * invq); r0.y = f2b(o0[1] * invq);
      r0.z = f2b(o0[2] * invq); r0.w = f2b(o0[3] * invq);
      r1.x = f2b(o1[0] * invq); r1.y = f2b(o1[1] * invq);
      r1.z = f2b(o1[2] * invq); r1.w = f2b(o1[3] * invq);
      ushort* ob = out + (size_t)(win * NTOK + q) * C + head * HD;
      *reinterpret_cast<ushort4*>(ob + dbase)      = r0;
      *reinterpret_cast<ushort4*>(ob + 16 + dbase) = r1;
    }
  }
}

// ---------------- launcher ----------------
extern "C" void kernel_launch(void* const* d_in, const int* in_sizes, int n_in,
                              void* d_out, int out_size, void* d_ws, size_t ws_size,
                              hipStream_t stream) {
  const float* x     = (const float*)d_in[0];
  const float* n1w   = (const float*)d_in[1];
  const float* n1b   = (const float*)d_in[2];
  const float* qkvw  = (const float*)d_in[3];
  const float* qkvb  = (const float*)d_in[4];
  const float* rpb   = (const float*)d_in[5];
  const float* projw = (const float*)d_in[6];
  const float* projb = (const float*)d_in[7];
  const float* n2w   = (const float*)d_in[8];
  const float* n2b   = (const float*)d_in[9];
  const float* w1    = (const float*)d_in[10];
  const float* b1    = (const float*)d_in[11];
  const float* w2    = (const float*)d_in[12];
  const float* b2    = (const float*)d_in[13];
  const int*   rel   = (const int*)d_in[14];

  char* ws = (char*)d_ws;
  constexpr size_t SZ_ACT  = (size_t)ROWS * C * 2;              // 11,239,424 (bf16 activations)
  constexpr size_t SZ_BIAS = (size_t)4 * NT * NT * 64 * 16;     // 1,982,464 (reordered f32x4)

  ushort* lnbuf  = (ushort*)(ws);                           // LN1 out
  ushort* Qb     = (ushort*)(ws + SZ_ACT);
  ushort* Kb     = (ushort*)(ws + 2 * SZ_ACT);
  ushort* Vb     = (ushort*)(ws + 3 * SZ_ACT);
  f32x4*  biasr  = (f32x4*)(ws + 4 * SZ_ACT);
  size_t off_att = (4 * SZ_ACT + SZ_BIAS + 255) & ~(size_t)255;
  ushort* attout = (ushort*)(ws + off_att);
  size_t off_y   = off_att + SZ_ACT;
  float*  y      = (float*)(ws + off_y);
  size_t off_w   = off_y + (size_t)ROWS * C * 4;
  ushort* wqkv   = (ushort*)(ws + off_w);
  ushort* wproj  = (ushort*)(ws + off_w + 98304);
  ushort* wm1    = (ushort*)(ws + off_w + 131072);
  ushort* wm2    = (ushort*)(ws + off_w + 262144);
  float*  outp   = (float*)d_out;

  cvt_kernel<<<768, 256, 0, stream>>>(qkvw, projw, w1, w2, wqkv, wproj, wm1, wm2);
  bias_kernel<<<(4 * NT * NT * 64 + 255) / 256, 256, 0, stream>>>(rel, rpb, (float4*)biasr);
  ln_kernel<true><<<ROWS / 4, 256, 0, stream>>>(x, n1w, n1b, lnbuf);
  gemm_kernel<128, 0><<<dim3(343, 3), 256, 0, stream>>>(lnbuf, wqkv, qkvb, nullptr, Qb, Kb, Vb, nullptr);
  attn_kernel<<<512, 512, 0, stream>>>(Qb, Kb, Vb, biasr, attout);
  gemm_kernel<128, 1><<<dim3(343, 1), 256, 0, stream>>>(attout, wproj, projb, x, nullptr, nullptr, nullptr, y);
  mlp_kernel<<<ROWS / 64, 256, 0, stream>>>(y, n2w, n2b, wm1, b1, wm2, b2, outp);
}

// Round 7
// 128.003 us; speedup vs baseline: 4.8562x; 1.0751x over previous
//
#include <hip/hip_runtime.h>

typedef __bf16 bfv8 __attribute__((ext_vector_type(8)));
typedef float f32x4 __attribute__((ext_vector_type(4)));
#define MFMA16(a,b,c) __builtin_amdgcn_mfma_f32_16x16x32_bf16(a,b,c,0,0,0)

constexpr int C      = 128;
constexpr int HD     = 32;
constexpr int NTOK   = 343;     // tokens per window (7^3)
constexpr int ROWS   = 43904;   // B*H*W*D = 2*28^3
constexpr int HIDDEN = 512;
constexpr float SCALE = 0.17677669529663687f;  // 32^-0.5
constexpr float EPS   = 1e-5f;
constexpr int NT = 22;          // 16-row tiles per window (ceil(343/16))

static __device__ __forceinline__ float b2f(ushort u) {
  union { unsigned int i; float f; } x; x.i = ((unsigned int)u) << 16; return x.f;
}
static __device__ __forceinline__ ushort f2b(float f) {
  union { float f; unsigned int i; } x; x.f = f;
  unsigned int r = x.i + 0x7fffu + ((x.i >> 16) & 1u);
  return (ushort)(r >> 16);
}

// dest row (window layout) -> source row (original layout), includes roll by 3
static __device__ __forceinline__ int perm_row(int row) {
  int win = row / NTOK, tok = row - win * NTOK;
  int bb = win >> 6, wi = win & 63;
  int a  = wi >> 4, w2 = (wi >> 2) & 3, c2 = wi & 3;
  int t1 = tok / 49, rem = tok - t1 * 49;
  int t2 = rem / 7,  t3 = rem - t2 * 7;
  int gh = a * 7 + t1 + 3;  if (gh >= 28) gh -= 28;
  int gw = w2 * 7 + t2 + 3; if (gw >= 28) gw -= 28;
  int gd = c2 * 7 + t3 + 3; if (gd >= 28) gd -= 28;
  return bb * 21952 + gh * 784 + gw * 28 + gd;
}

// ---------------- f32 -> bf16 weight conversion ----------------
__global__ __launch_bounds__(256) void cvt_kernel(const float* __restrict__ s0,
                                                  const float* __restrict__ s1,
                                                  const float* __restrict__ s2,
                                                  const float* __restrict__ s3,
                                                  ushort* __restrict__ d0,
                                                  ushort* __restrict__ d1,
                                                  ushort* __restrict__ d2,
                                                  ushort* __restrict__ d3) {
  int t = blockIdx.x * 256 + threadIdx.x;
  if (t < 49152)       d0[t]          = f2b(s0[t]);
  else if (t < 65536)  d1[t - 49152]  = f2b(s1[t - 49152]);
  else if (t < 131072) d2[t - 65536]  = f2b(s2[t - 65536]);
  else                 d3[t - 131072] = f2b(s3[t - 131072]);
}

// ------- bias reordered into MFMA C-fragment order, mask baked in -------
__global__ __launch_bounds__(256) void bias_kernel(const int* __restrict__ rel,
                                                   const float* __restrict__ tab,
                                                   float4* __restrict__ biasr) {
  int t = blockIdx.x * 256 + threadIdx.x;
  if (t >= 4 * NT * NT * 64) return;
  int lane = t & 63;
  int nt   = (t >> 6) % NT;
  int mt   = ((t >> 6) / NT) % NT;
  int head = t / (64 * NT * NT);
  int k  = nt * 16 + (lane & 15);
  int qb = mt * 16 + (lane >> 4) * 4;
  float vv[4];
  #pragma unroll
  for (int r = 0; r < 4; ++r) {
    int q = qb + r;
    if (q < NTOK && k < NTOK) {
      int idx = rel[q * NTOK + k];
      vv[r] = tab[idx * 4 + head];
    } else {
      vv[r] = -3e38f;
    }
  }
  biasr[t] = make_float4(vv[0], vv[1], vv[2], vv[3]);
}

// ---------------- LayerNorm with roll+window permutation, f32 in -> bf16 out ----
template<bool PERM>
__global__ __launch_bounds__(256) void ln_kernel(const float* __restrict__ in,
                                                 const float* __restrict__ w,
                                                 const float* __restrict__ b,
                                                 ushort* __restrict__ out) {
  int wid = threadIdx.x >> 6, lane = threadIdx.x & 63;
  int row = blockIdx.x * 4 + wid;
  int src = PERM ? perm_row(row) : row;
  float2 v = *reinterpret_cast<const float2*>(in + (size_t)src * C + lane * 2);
  float s = v.x + v.y, q = v.x * v.x + v.y * v.y;
  #pragma unroll
  for (int off = 32; off; off >>= 1) { s += __shfl_xor(s, off); q += __shfl_xor(q, off); }
  float mu = s * (1.0f / 128.0f);
  float var = q * (1.0f / 128.0f) - mu * mu;
  float rs = rsqrtf(var + EPS);
  int c = lane * 2;
  ushort2 ov;
  ov.x = f2b((v.x - mu) * rs * w[c]     + b[c]);
  ov.y = f2b((v.y - mu) * rs * w[c + 1] + b[c + 1]);
  *reinterpret_cast<ushort2*>(out + (size_t)row * C + c) = ov;
}

// ---------------- 128x128-tile bf16 MFMA GEMM with fused epilogues ----------------
// EPI 0: QKV scatter (bf16, Q pre-scaled)  1: proj + residual(f32 x) -> f32 y, un-permute
template<int KTOT, int EPI>
__global__ __launch_bounds__(256) void gemm_kernel(const ushort* __restrict__ A,
                                                   const ushort* __restrict__ W,
                                                   const float* __restrict__ bias,
                                                   const float* __restrict__ X,
                                                   ushort* __restrict__ O0,
                                                   ushort* __restrict__ O1,
                                                   ushort* __restrict__ O2,
                                                   float* __restrict__ OF) {
  __shared__ ushort Al[128][136];
  __shared__ ushort Bl[128][136];
  const int m0 = blockIdx.x * 128, n0 = blockIdx.y * 128;
  const int tid = threadIdx.x, lane = tid & 63, wid = tid >> 6;
  const int wr = wid >> 1, wc = wid & 1;
  const int lr = lane & 15, kb0 = (lane >> 4) * 8;
  const int sr = tid >> 4, sc = (tid & 15) * 8;
  f32x4 acc[4][4] = {};
  for (int kc = 0; kc < KTOT; kc += 128) {
    #pragma unroll
    for (int p = 0; p < 8; ++p) {
      int row = p * 16 + sr;
      *reinterpret_cast<int4*>(&Al[row][sc]) =
          *reinterpret_cast<const int4*>(&A[(size_t)(m0 + row) * KTOT + kc + sc]);
      *reinterpret_cast<int4*>(&Bl[row][sc]) =
          *reinterpret_cast<const int4*>(&W[(size_t)(n0 + row) * KTOT + kc + sc]);
    }
    __syncthreads();
    #pragma unroll
    for (int kk = 0; kk < 4; ++kk) {
      int kb = kk * 32 + kb0;
      bfv8 a[4], b[4];
      #pragma unroll
      for (int m = 0; m < 4; ++m) a[m] = *reinterpret_cast<const bfv8*>(&Al[wr * 64 + m * 16 + lr][kb]);
      #pragma unroll
      for (int n = 0; n < 4; ++n) b[n] = *reinterpret_cast<const bfv8*>(&Bl[wc * 64 + n * 16 + lr][kb]);
      #pragma unroll
      for (int m = 0; m < 4; ++m)
        #pragma unroll
        for (int n = 0; n < 4; ++n)
          acc[m][n] = MFMA16(a[m], b[n], acc[m][n]);
    }
    __syncthreads();
  }
  #pragma unroll
  for (int m = 0; m < 4; ++m)
    #pragma unroll
    for (int n = 0; n < 4; ++n)
      #pragma unroll
      for (int r = 0; r < 4; ++r) {
        int gm = m0 + wr * 64 + m * 16 + (lane >> 4) * 4 + r;
        int gn = n0 + wc * 64 + n * 16 + (lane & 15);
        float v = acc[m][n][r] + bias[gn];
        if (EPI == 0) {
          int which = gn >> 7, head = (gn >> 5) & 3, d = gn & 31;
          if (which == 0) v *= SCALE;     // fold attention scale into Q
          int win = gm / NTOK, tok = gm - win * NTOK;
          ushort* dst = (which == 0) ? O0 : (which == 1) ? O1 : O2;
          dst[((win * 4 + head) * NTOK + tok) * HD + d] = f2b(v);
        } else {
          int orig = perm_row(gm);
          OF[(size_t)orig * C + gn] = v + X[(size_t)orig * C + gn];
        }
      }
}

// ---------------- fused LN2 + MLP1 + gelu + MLP2 + residual ----------------
// 128 rows/block, 512 threads (8 waves x 16 rows). Grid = 343 blocks -> fully
// resident (2 blocks/CU, 16 waves/CU). A-tile and H-tile share one LDS buffer
// (A fragments live in registers before chunk 0). h1 never touches HBM.
__global__ __launch_bounds__(512) void mlp_kernel(const float* __restrict__ y,
                                                  const float* __restrict__ nw,
                                                  const float* __restrict__ nb,
                                                  const ushort* __restrict__ W1,
                                                  const float* __restrict__ b1,
                                                  const ushort* __restrict__ W2,
                                                  const float* __restrict__ b2,
                                                  float* __restrict__ outp) {
  __shared__ ushort AH[128][140];     // LN2 out, then per-chunk gelu(h1)
  __shared__ ushort Wl[128][140];     // W1c / W2c, time-multiplexed
  const int m0 = blockIdx.x * 128;
  const int tid = threadIdx.x, lane = tid & 63, wave = tid >> 6;
  // ---- LN2: 4 threads per row, one pass over 128 rows (wave w owns rows 16w..16w+15) ----
  {
    int row = tid >> 2, sub = tid & 3;
    const float* yr = y + (size_t)(m0 + row) * C + sub * 32;
    float4 v[8];
    float s = 0.f, q = 0.f;
    #pragma unroll
    for (int j = 0; j < 8; ++j) {
      v[j] = *reinterpret_cast<const float4*>(yr + j * 4);
      s += v[j].x + v[j].y + v[j].z + v[j].w;
      q += v[j].x * v[j].x + v[j].y * v[j].y + v[j].z * v[j].z + v[j].w * v[j].w;
    }
    s += __shfl_xor(s, 1); q += __shfl_xor(q, 1);
    s += __shfl_xor(s, 2); q += __shfl_xor(q, 2);
    float mu = s * (1.0f / 128.0f);
    float var = q * (1.0f / 128.0f) - mu * mu;
    float rs = rsqrtf(var + EPS);
    #pragma unroll
    for (int j = 0; j < 8; ++j) {
      int c = sub * 32 + j * 4;
      ushort4 o;
      o.x = f2b((v[j].x - mu) * rs * nw[c]     + nb[c]);
      o.y = f2b((v[j].y - mu) * rs * nw[c + 1] + nb[c + 1]);
      o.z = f2b((v[j].z - mu) * rs * nw[c + 2] + nb[c + 2]);
      o.w = f2b((v[j].w - mu) * rs * nw[c + 3] + nb[c + 3]);
      *reinterpret_cast<ushort4*>(&AH[row][c]) = o;
    }
  }
  const int lr = lane & 15, kb0 = (lane >> 4) * 8;
  const int key = lane & 15, qr4 = (lane >> 4) * 4;
  const int sr = tid >> 4, sc = (tid & 15) * 8;
  // A fragments (same-wave rows -> ordered by lgkmcnt, no barrier needed)
  bfv8 af[4];
  #pragma unroll
  for (int kk = 0; kk < 4; ++kk)
    af[kk] = *reinterpret_cast<const bfv8*>(&AH[wave * 16 + lr][kk * 32 + kb0]);
  f32x4 acc[8] = {};
  for (int c = 0; c < 4; ++c) {
    __syncthreads();   // previous chunk's Wl readers done (no-op hazard at c==0)
    #pragma unroll
    for (int p = 0; p < 4; ++p) {
      int row = p * 32 + sr;
      *reinterpret_cast<int4*>(&Wl[row][sc]) =
          *reinterpret_cast<const int4*>(&W1[(size_t)(c * 128 + row) * 128 + sc]);
    }
    __syncthreads();
    #pragma unroll
    for (int n = 0; n < 8; ++n) {
      f32x4 h = {};
      #pragma unroll
      for (int kk = 0; kk < 4; ++kk)
        h = MFMA16(af[kk], *reinterpret_cast<const bfv8*>(&Wl[n * 16 + lr][kk * 32 + kb0]), h);
      #pragma unroll
      for (int r = 0; r < 4; ++r) {
        float val = h[r] + b1[c * 128 + n * 16 + key];
        float g = 0.5f * val * (1.0f + erff(val * 0.70710678118654752f));
        AH[wave * 16 + qr4 + r][n * 16 + key] = f2b(g);   // own rows
      }
    }
    bfv8 hf[4];
    #pragma unroll
    for (int kk = 0; kk < 4; ++kk)
      hf[kk] = *reinterpret_cast<const bfv8*>(&AH[wave * 16 + lr][kk * 32 + kb0]);  // same-wave dep
    __syncthreads();   // all waves done reading Wl(W1)
    #pragma unroll
    for (int p = 0; p < 4; ++p) {
      int row = p * 32 + sr;
      *reinterpret_cast<int4*>(&Wl[row][sc]) =
          *reinterpret_cast<const int4*>(&W2[(size_t)row * HIDDEN + c * 128 + sc]);
    }
    __syncthreads();
    #pragma unroll
    for (int n = 0; n < 8; ++n)
      #pragma unroll
      for (int kk = 0; kk < 4; ++kk)
        acc[n] = MFMA16(hf[kk], *reinterpret_cast<const bfv8*>(&Wl[n * 16 + lr][kk * 32 + kb0]), acc[n]);
  }
  #pragma unroll
  for (int n = 0; n < 8; ++n)
    #pragma unroll
    for (int r = 0; r < 4; ++r) {
      int gm = m0 + wave * 16 + qr4 + r;
      int gn = n * 16 + key;
      outp[(size_t)gm * C + gn] = acc[n][r] + b2[gn] + y[(size_t)gm * C + gn];
    }
}

// ---------------- windowed attention: one block (8 waves) per (window, head) ----------------
__global__ __launch_bounds__(512) void attn_kernel(const ushort* __restrict__ Q,
                                                   const ushort* __restrict__ K,
                                                   const ushort* __restrict__ V,
                                                   const f32x4* __restrict__ biasr,
                                                   ushort* __restrict__ out) {
  __shared__ ushort vt[32][360];       // V transposed: vt[d][token]
  __shared__ ushort pl[8][16][204];    // per-wave P phase-tile (16 q-rows x <=192 keys)
  const int wh = blockIdx.x;
  const int win = wh >> 2, head = wh & 3;
  const int tid = threadIdx.x, lane = tid & 63, wave = tid >> 6;
  if (tid < 352) {
    int t = tid;
    if (t < NTOK) {
      ushort tmp[32];
      const ushort* vr = V + ((size_t)wh * NTOK + t) * HD;
      *reinterpret_cast<int4*>(&tmp[0])  = *reinterpret_cast<const int4*>(vr);
      *reinterpret_cast<int4*>(&tmp[8])  = *reinterpret_cast<const int4*>(vr + 8);
      *reinterpret_cast<int4*>(&tmp[16]) = *reinterpret_cast<const int4*>(vr + 16);
      *reinterpret_cast<int4*>(&tmp[24]) = *reinterpret_cast<const int4*>(vr + 24);
      #pragma unroll
      for (int d = 0; d < 32; ++d) vt[d][t] = tmp[d];
    } else {
      #pragma unroll
      for (int d = 0; d < 32; ++d) vt[d][t] = 0;
    }
  }
  __syncthreads();
  const int lr = lane & 15, kb0 = (lane >> 4) * 8;
  const int key = lane & 15, qr4 = (lane >> 4) * 4;
  for (int mt = wave; mt < NT; mt += 8) {
    int qrow = mt * 16 + lr; if (qrow > 342) qrow = 342;   // clamp pad rows
    bfv8 aq = *reinterpret_cast<const bfv8*>(Q + ((size_t)wh * NTOK + qrow) * HD + kb0);
    const f32x4* bR = biasr + ((size_t)(head * NT + mt) * NT) * 64 + lane;
    float sm[4] = {0.f, 0.f, 0.f, 0.f};
    f32x4 o0 = {}, o1 = {};
    // ---- phase 0: keys 0..191 (nt 0..11) ----
    #pragma unroll
    for (int nt = 0; nt < 12; ++nt) {
      int krow = nt * 16 + lr;
      bfv8 bk = *reinterpret_cast<const bfv8*>(K + ((size_t)wh * NTOK + krow) * HD + kb0);
      f32x4 s = MFMA16(aq, bk, bR[nt * 64]);    // C operand = bias (+mask)
      int kcol = nt * 16 + key;
      #pragma unroll
      for (int r = 0; r < 4; ++r) {
        float p = __expf(s[r]);
        sm[r] += p;
        pl[wave][qr4 + r][kcol] = f2b(p);       // unnormalized
      }
    }
    #pragma unroll
    for (int kt = 0; kt < 6; ++kt) {
      bfv8 bp  = *reinterpret_cast<const bfv8*>(&pl[wave][lr][kt * 32 + kb0]);
      bfv8 av0 = *reinterpret_cast<const bfv8*>(&vt[lr][kt * 32 + kb0]);
      bfv8 av1 = *reinterpret_cast<const bfv8*>(&vt[16 + lr][kt * 32 + kb0]);
      o0 = MFMA16(av0, bp, o0);
      o1 = MFMA16(av1, bp, o1);
    }
    // ---- phase 1: keys 192..351 (nt 12..21) ----
    #pragma unroll
    for (int nt = 12; nt < NT; ++nt) {
      int krow = nt * 16 + lr; if (krow > 342) krow = 342;
      bfv8 bk = *reinterpret_cast<const bfv8*>(K + ((size_t)wh * NTOK + krow) * HD + kb0);
      f32x4 s = MFMA16(aq, bk, bR[nt * 64]);
      int kcol = (nt - 12) * 16 + key;
      #pragma unroll
      for (int r = 0; r < 4; ++r) {
        float p = __expf(s[r]);
        sm[r] += p;
        pl[wave][qr4 + r][kcol] = f2b(p);
      }
    }
    #pragma unroll
    for (int kt = 0; kt < 5; ++kt) {
      bfv8 bp  = *reinterpret_cast<const bfv8*>(&pl[wave][lr][kt * 32 + kb0]);
      bfv8 av0 = *reinterpret_cast<const bfv8*>(&vt[lr][192 + kt * 32 + kb0]);
      bfv8 av1 = *reinterpret_cast<const bfv8*>(&vt[16 + lr][192 + kt * 32 + kb0]);
      o0 = MFMA16(av0, bp, o0);
      o1 = MFMA16(av1, bp, o1);
    }
    #pragma unroll
    for (int r = 0; r < 4; ++r) {
      #pragma unroll
      for (int off = 1; off < 16; off <<= 1) sm[r] += __shfl_xor(sm[r], off);
    }
    float inv[4];
    #pragma unroll
    for (int r = 0; r < 4; ++r) inv[r] = 1.0f / sm[r];
    int qcol = lane & 15;
    int srcl = (qcol >> 2) << 4;
    float i0 = __shfl(inv[0], srcl), i1 = __shfl(inv[1], srcl);
    float i2 = __shfl(inv[2], srcl), i3 = __shfl(inv[3], srcl);
    float invq = (qcol & 2) ? ((qcol & 1) ? i3 : i2) : ((qcol & 1) ? i1 : i0);
    int q = mt * 16 + qcol;
    if (q < NTOK) {
      int dbase = qr4;
      ushort4 r0, r1;
      r0.x = f2b(o0[0] * invq); r0.y = f2b(o0[1] * invq);
      r0.z = f2b(o0[2] * invq); r0.w = f2b(o0[3] * invq);
      r1.x = f2b(o1[0] * invq); r1.y = f2b(o1[1] * invq);
      r1.z = f2b(o1[2] * invq); r1.w = f2b(o1[3] * invq);
      ushort* ob = out + (size_t)(win * NTOK + q) * C + head * HD;
      *reinterpret_cast<ushort4*>(ob + dbase)      = r0;
      *reinterpret_cast<ushort4*>(ob + 16 + dbase) = r1;
    }
  }
}

// ---------------- launcher ----------------
extern "C" void kernel_launch(void* const* d_in, const int* in_sizes, int n_in,
                              void* d_out, int out_size, void* d_ws, size_t ws_size,
                              hipStream_t stream) {
  const float* x     = (const float*)d_in[0];
  const float* n1w   = (const float*)d_in[1];
  const float* n1b   = (const float*)d_in[2];
  const float* qkvw  = (const float*)d_in[3];
  const float* qkvb  = (const float*)d_in[4];
  const float* rpb   = (const float*)d_in[5];
  const float* projw = (const float*)d_in[6];
  const float* projb = (const float*)d_in[7];
  const float* n2w   = (const float*)d_in[8];
  const float* n2b   = (const float*)d_in[9];
  const float* w1    = (const float*)d_in[10];
  const float* b1    = (const float*)d_in[11];
  const float* w2    = (const float*)d_in[12];
  const float* b2    = (const float*)d_in[13];
  const int*   rel   = (const int*)d_in[14];

  char* ws = (char*)d_ws;
  constexpr size_t SZ_ACT  = (size_t)ROWS * C * 2;              // 11,239,424 (bf16 activations)
  constexpr size_t SZ_BIAS = (size_t)4 * NT * NT * 64 * 16;     // 1,982,464 (reordered f32x4)

  ushort* lnbuf  = (ushort*)(ws);                           // LN1 out
  ushort* Qb     = (ushort*)(ws + SZ_ACT);
  ushort* Kb     = (ushort*)(ws + 2 * SZ_ACT);
  ushort* Vb     = (ushort*)(ws + 3 * SZ_ACT);
  f32x4*  biasr  = (f32x4*)(ws + 4 * SZ_ACT);
  size_t off_att = (4 * SZ_ACT + SZ_BIAS + 255) & ~(size_t)255;
  ushort* attout = (ushort*)(ws + off_att);
  size_t off_y   = off_att + SZ_ACT;
  float*  y      = (float*)(ws + off_y);
  size_t off_w   = off_y + (size_t)ROWS * C * 4;
  ushort* wqkv   = (ushort*)(ws + off_w);
  ushort* wproj  = (ushort*)(ws + off_w + 98304);
  ushort* wm1    = (ushort*)(ws + off_w + 131072);
  ushort* wm2    = (ushort*)(ws + off_w + 262144);
  float*  outp   = (float*)d_out;

  cvt_kernel<<<768, 256, 0, stream>>>(qkvw, projw, w1, w2, wqkv, wproj, wm1, wm2);
  bias_kernel<<<(4 * NT * NT * 64 + 255) / 256, 256, 0, stream>>>(rel, rpb, (float4*)biasr);
  ln_kernel<true><<<ROWS / 4, 256, 0, stream>>>(x, n1w, n1b, lnbuf);
  gemm_kernel<128, 0><<<dim3(343, 3), 256, 0, stream>>>(lnbuf, wqkv, qkvb, nullptr, Qb, Kb, Vb, nullptr);
  attn_kernel<<<512, 512, 0, stream>>>(Qb, Kb, Vb, biasr, attout);
  gemm_kernel<128, 1><<<dim3(343, 1), 256, 0, stream>>>(attout, wproj, projb, x, nullptr, nullptr, nullptr, y);
  mlp_kernel<<<ROWS / 128, 512, 0, stream>>>(y, n2w, n2b, wm1, b1, wm2, b2, outp);
}